// Round 1
// baseline (10232.207 us; speedup 1.0000x reference)
//
#include <hip/hip_runtime.h>
#include <math.h>

// Problem constants (from reference)
#define H_    8
#define DK_   16
#define DM_   128
#define DI_   512
#define B_    64
#define S_    2048
#define NTOK  131072          // B_*S_
#define EPS_  1e-6f
#define INV_TEMP 0.5f         // TEMP = 0.5*sqrt(16) = 2.0

#define WBAR() __builtin_amdgcn_wave_barrier()

typedef __attribute__((ext_vector_type(8))) _Float16 half8;
typedef __attribute__((ext_vector_type(4))) float f32x4;

struct P4 { const float* p[4]; };

// ---------------------------------------------------------------------------
// Pack a K x N f32 weight (row-major) into fp16 B-fragment order for
// mfma_f32_16x16x32_f16: flat[((nt*(K/32)+kt)*64 + lane)*8 + j] =
//   W[kt*32 + (lane>>4)*8 + j][nt*16 + (lane&15)].  blockIdx.y = layer.
// ---------------------------------------------------------------------------
__global__ __launch_bounds__(256) void pack_b(
    const float* __restrict__ W, _Float16* __restrict__ out, int K, int N)
{
    long base = (long)blockIdx.y * K * N;
    int idx = blockIdx.x * 256 + threadIdx.x;
    if (idx >= K * N) return;
    int j = idx & 7;
    int lane = (idx >> 3) & 63;
    int t = idx >> 9;                 // tile = nt*(K/32)+kt
    int KT = K >> 5;
    int nt = t / KT, kt = t - nt * KT;
    int k = kt * 32 + (lane >> 4) * 8 + j;
    int n = nt * 16 + (lane & 15);
    out[base + idx] = (_Float16)W[base + (long)k * N + n];
}

// ---------------------------------------------------------------------------
// Kernel A: per 64-token tile, 4 waves, each wave owns 16 token rows.
// ALL phases (load, folded K/V proj, LN1 via 4-lane shfl reduce, Q proj,
// score partials) are wave-local -> single __syncthreads before the
// cross-wave partial-score reduction + atomicAdd.
// ---------------------------------------------------------------------------
__global__ __launch_bounds__(256) void enc_qkv_attn(
    P4 qp, int ldq, P4 kp, int ldk,
    _Float16* __restrict__ v8, float* __restrict__ att,
    const float* __restrict__ Wq, const float* __restrict__ Wk,
    const float* __restrict__ Wv,
    const float* __restrict__ lng, const float* __restrict__ lnb)
{
    __shared__ float sx[64 * 128];
    __shared__ float sk8[64 * 64];
    __shared__ float spart[4 * 128 * 8];

    const int tid  = threadIdx.x;
    const int w    = tid >> 6;          // wave 0..3
    const int lane = tid & 63;
    const int bx   = blockIdx.x;
    const int s    = bx >> 11;
    const int blk  = bx & 2047;
    const long tok0 = (long)blk * 64;
    const int b = blk >> 5;
    const int tw0 = w * 16;             // wave-owned rows tw0..tw0+15

    const float* qb = qp.p[s];
    const float* kb = kp.p[s];
    _Float16* v8s = v8 + (long)s * ((long)NTOK * 64) + tok0 * 64;
    float* atts = att + (long)s * (B_ * 1024) + (long)b * 1024;

    // ---- phase 1: wave-local load of this wave's 16 k-input rows ----
    #pragma unroll
    for (int r = 0; r < 8; ++r) {
        int u = r * 64 + lane;
        int tok = tw0 + (u >> 5), c4 = u & 31;
        float4 v = *(const float4*)(kb + (tok0 + tok) * (long)ldk + c4 * 4);
        *(float4*)(sx + tok * 128 + c4 * 4) = v;
    }
    WBAR();

    // ---- phase 2: folded K/V projection (pair-mean folded into weights) ----
    {
        const int j = lane;
        float ka[16], va[16];
        #pragma unroll
        for (int t = 0; t < 16; ++t) { ka[t] = 0.f; va[t] = 0.f; }
        for (int i = 0; i < 128; i += 4) {
            float wk[4], wv[4];
            #pragma unroll
            for (int u = 0; u < 4; ++u) {
                float2 a = *(const float2*)(Wk + (long)(i + u) * 128 + 2 * j);
                float2 c = *(const float2*)(Wv + (long)(i + u) * 128 + 2 * j);
                wk[u] = 0.5f * (a.x + a.y);
                wv[u] = 0.5f * (c.x + c.y);
            }
            #pragma unroll
            for (int t = 0; t < 16; ++t) {
                float4 xv = *(const float4*)(sx + (tw0 + t) * 128 + i);
                ka[t] += xv.x * wk[0] + xv.y * wk[1] + xv.z * wk[2] + xv.w * wk[3];
                va[t] += xv.x * wv[0] + xv.y * wv[1] + xv.z * wv[2] + xv.w * wv[3];
            }
        }
        #pragma unroll
        for (int t = 0; t < 16; ++t) {
            int tok = tw0 + t;
            sk8[tok * 64 + j] = ka[t];
            v8s[(long)tok * 64 + j] = (_Float16)va[t];
        }
    }
    WBAR();

    // ---- phase 3: reload q rows if q-input differs ----
    if (qb != kb || ldq != ldk) {
        #pragma unroll
        for (int r = 0; r < 8; ++r) {
            int u = r * 64 + lane;
            int tok = tw0 + (u >> 5), c4 = u & 31;
            float4 v = *(const float4*)(qb + (tok0 + tok) * (long)ldq + c4 * 4);
            *(float4*)(sx + tok * 128 + c4 * 4) = v;
        }
        WBAR();
    }

    // ---- phase 4: LN1, wave-local (4 lanes per token, shfl_xor reduce) ----
    {
        const int t = lane >> 2, part = lane & 3;
        float* xr = sx + (tw0 + t) * 128 + part * 32;
        float sum = 0.f;
        #pragma unroll
        for (int i = 0; i < 32; i += 4) {
            float4 v = *(const float4*)(xr + i);
            sum += v.x + v.y + v.z + v.w;
        }
        sum += __shfl_xor(sum, 1); sum += __shfl_xor(sum, 2);
        const float mu = sum * (1.f / 128.f);
        float ss = 0.f;
        #pragma unroll
        for (int i = 0; i < 32; i += 4) {
            float4 v = *(const float4*)(xr + i);
            float d0 = v.x - mu, d1 = v.y - mu, d2 = v.z - mu, d3 = v.w - mu;
            ss += d0 * d0 + d1 * d1 + d2 * d2 + d3 * d3;
        }
        ss += __shfl_xor(ss, 1); ss += __shfl_xor(ss, 2);
        const float rs = rsqrtf(ss * (1.f / 128.f) + EPS_);
        #pragma unroll
        for (int i = 0; i < 32; i += 4) {
            float4 v  = *(const float4*)(xr + i);
            float4 g  = *(const float4*)(lng + part * 32 + i);
            float4 bb = *(const float4*)(lnb + part * 32 + i);
            v.x = (v.x - mu) * rs * g.x + bb.x;
            v.y = (v.y - mu) * rs * g.y + bb.y;
            v.z = (v.z - mu) * rs * g.z + bb.z;
            v.w = (v.w - mu) * rs * g.w + bb.w;
            *(float4*)(xr + i) = v;
        }
    }
    WBAR();

    // ---- phase 5: Q proj + score partials (wave-local rows) ----
    {
        const int j = lane;
        float qa0[16], qa1[16];
        #pragma unroll
        for (int t = 0; t < 16; ++t) { qa0[t] = 0.f; qa1[t] = 0.f; }
        for (int i = 0; i < 128; i += 4) {
            float w0[4], w1[4];
            #pragma unroll
            for (int u = 0; u < 4; ++u) {
                w0[u] = Wq[(long)(i + u) * 128 + j];
                w1[u] = Wq[(long)(i + u) * 128 + j + 64];
            }
            #pragma unroll
            for (int t = 0; t < 16; ++t) {
                float4 xv = *(const float4*)(sx + (tw0 + t) * 128 + i);
                qa0[t] += xv.x * w0[0] + xv.y * w0[1] + xv.z * w0[2] + xv.w * w0[3];
                qa1[t] += xv.x * w1[0] + xv.y * w1[1] + xv.z * w1[2] + xv.w * w1[3];
            }
        }
        #pragma unroll
        for (int fi = 0; fi < 2; ++fi) {
            int f = j + fi * 64;
            int h = f >> 4;
            float p[8];
            #pragma unroll
            for (int e = 0; e < 8; ++e) p[e] = 0.f;
            #pragma unroll
            for (int t = 0; t < 16; ++t) {
                int tok = tw0 + t;
                float4 k0 = *(const float4*)(sk8 + tok * 64 + h * 8);
                float4 k1 = *(const float4*)(sk8 + tok * 64 + h * 8 + 4);
                float q = fi ? qa1[t] : qa0[t];
                p[0] += q * k0.x; p[1] += q * k0.y; p[2] += q * k0.z; p[3] += q * k0.w;
                p[4] += q * k1.x; p[5] += q * k1.y; p[6] += q * k1.z; p[7] += q * k1.w;
            }
            #pragma unroll
            for (int e = 0; e < 8; ++e) spart[(w * 128 + f) * 8 + e] = p[e];
        }
    }
    __syncthreads();    // the ONLY block-wide barrier: cross-wave reduce
    for (int idx = tid; idx < 1024; idx += 256) {
        float v = spart[idx] + spart[1024 + idx] + spart[2048 + idx] + spart[3072 + idx];
        atomicAdd(atts + idx, v);
    }
}

// ---------------------------------------------------------------------------
// Kernel C (MFMA, fp16): per 64-token tile, 4 waves, wave = M=16 tokens.
// All LDS round-trips (xn staging, FFN h staging) are WAVE-LOCAL (wave w
// writes and reads only rows w*16..w*16+15), so no __syncthreads is needed
// except the softmax s_att broadcast. s_xn/s_h merged into one buffer
// (xn is dead after xfrag load): LDS 38.9 KB -> 21.5 KB.
// ---------------------------------------------------------------------------
__global__ __launch_bounds__(256) void enc_post_mfma(
    P4 xp, int ldx, P4 op, int ldo,
    const _Float16* __restrict__ v8, const float* __restrict__ att,
    const _Float16* __restrict__ Wfcp,
    const float* __restrict__ lng, const float* __restrict__ lnb,
    const _Float16* __restrict__ W1p, const float* __restrict__ bv1,
    const _Float16* __restrict__ W2p, const float* __restrict__ bv2)
{
    __shared__ float s_att[1024];
    __shared__ _Float16 s_buf[64 * 136];   // stride 136 breaks bank conflicts

    const int tid  = threadIdx.x;
    const int w    = tid >> 6;          // wave 0..3
    const int lane = tid & 63;
    const int quad = lane >> 4, l16 = lane & 15;
    const int bx   = blockIdx.x;
    const int s    = bx >> 11;          // 2048 blocks per stream
    const int blk  = bx & 2047;
    const long tok0 = (long)blk * 64;
    const int b = blk >> 5;

    const float* xb = xp.p[s];
    float* ob = (float*)op.p[s];
    const _Float16* v8s = v8 + (long)s * ((long)NTOK * 64) + tok0 * 64;
    const float* atts = att + (long)s * (B_ * 1024) + (long)b * 1024;

    const int tA = w * 16 + l16;        // this lane's token row

    // ---- early global loads (independent of s_att): v rows + LN2 params ----
    half8 hvv[8];
    {
        const _Float16* vrow = v8s + (long)tA * 64;
        #pragma unroll
        for (int j = 0; j < 8; ++j) hvv[j] = *(const half8*)(vrow + j * 8);
    }
    float gv[8], bvv[8], bb2[8];
    #pragma unroll
    for (int nt = 0; nt < 8; ++nt) {
        gv[nt]  = lng[nt * 16 + l16];
        bvv[nt] = lnb[nt * 16 + l16];
        bb2[nt] = bv2[nt * 16 + l16];
    }

    if (tid < 128) {                    // softmax rows h*16+d
        float sc[8];
        #pragma unroll
        for (int e = 0; e < 8; ++e) sc[e] = atts[tid * 8 + e] * INV_TEMP;
        float m = sc[0];
        #pragma unroll
        for (int e = 1; e < 8; ++e) m = fmaxf(m, sc[e]);
        float sum = 0.f;
        #pragma unroll
        for (int e = 0; e < 8; ++e) { sc[e] = expf(sc[e] - m); sum += sc[e]; }
        float inv = 1.f / sum;
        #pragma unroll
        for (int e = 0; e < 8; ++e) s_att[tid * 8 + e] = sc[e] * inv;
    }
    __syncthreads();                    // the ONLY block-wide barrier

    // ---- attn apply -> A fragments. Lane token tA, features kt*32+quad*8+j.
    half8 afrag[4];
    {
        float ao[4][8];
        #pragma unroll
        for (int j = 0; j < 8; ++j) {
            half8 hv = hvv[j];
            float v0 = (float)hv[0], v1 = (float)hv[1], v2 = (float)hv[2], v3 = (float)hv[3];
            float v4 = (float)hv[4], v5 = (float)hv[5], v6 = (float)hv[6], v7 = (float)hv[7];
            #pragma unroll
            for (int kt = 0; kt < 4; ++kt) {
                const float* ar = s_att + (j * 16 + kt * 4 + quad) * 8;
                float4 a0 = *(const float4*)ar;
                float4 a1 = *(const float4*)(ar + 4);
                ao[kt][j] = a0.x * v0 + a0.y * v1 + a0.z * v2 + a0.w * v3
                          + a1.x * v4 + a1.y * v5 + a1.z * v6 + a1.w * v7;
            }
        }
        #pragma unroll
        for (int kt = 0; kt < 4; ++kt)
            #pragma unroll
            for (int j = 0; j < 8; ++j)
                afrag[kt][j] = (_Float16)ao[kt][j];
    }

    // ---- Wfc: D(16x128) = A(16x128) x Wfc(128x128) ----
    f32x4 yacc[8];
    #pragma unroll
    for (int nt = 0; nt < 8; ++nt) {
        f32x4 c = {0.f, 0.f, 0.f, 0.f};
        #pragma unroll
        for (int kt = 0; kt < 4; ++kt) {
            half8 bf = *(const half8*)(Wfcp + ((nt * 4 + kt) * 64 + lane) * 8);
            c = __builtin_amdgcn_mfma_f32_16x16x32_f16(afrag[kt], bf, c, 0, 0, 0);
        }
        yacc[nt] = c;
    }

    // ---- residual: y[nt][r], token = w*16+quad*4+r, feature = nt*16+l16 ----
    float y[8][4];
    #pragma unroll
    for (int r = 0; r < 4; ++r) {
        const float* xrow = xb + (tok0 + w * 16 + quad * 4 + r) * (long)ldx;
        #pragma unroll
        for (int nt = 0; nt < 8; ++nt)
            y[nt][r] = yacc[nt][r] + xrow[nt * 16 + l16];
    }

    // ---- LN2 in registers: row reduce over 8 in-lane cols + 16-lane butterfly
    float mu[4], rs[4];
    #pragma unroll
    for (int r = 0; r < 4; ++r) {
        float sm = 0.f;
        #pragma unroll
        for (int nt = 0; nt < 8; ++nt) sm += y[nt][r];
        sm += __shfl_xor(sm, 1); sm += __shfl_xor(sm, 2);
        sm += __shfl_xor(sm, 4); sm += __shfl_xor(sm, 8);
        mu[r] = sm * (1.f / 128.f);
        float ss = 0.f;
        #pragma unroll
        for (int nt = 0; nt < 8; ++nt) { float d = y[nt][r] - mu[r]; ss += d * d; }
        ss += __shfl_xor(ss, 1); ss += __shfl_xor(ss, 2);
        ss += __shfl_xor(ss, 4); ss += __shfl_xor(ss, 8);
        rs[r] = rsqrtf(ss * (1.f / 128.f) + EPS_);
    }

    // ---- xn -> LDS (fp16, padded, WAVE-LOCAL rows) for FFN1 A-fragments ----
    #pragma unroll
    for (int nt = 0; nt < 8; ++nt)
        #pragma unroll
        for (int r = 0; r < 4; ++r) {
            float xnv = (y[nt][r] - mu[r]) * rs[r] * gv[nt] + bvv[nt];
            s_buf[(w * 16 + quad * 4 + r) * 136 + nt * 16 + l16] = (_Float16)xnv;
        }
    WBAR();

    half8 xfrag[4];
    #pragma unroll
    for (int kt = 0; kt < 4; ++kt)
        xfrag[kt] = *(const half8*)(s_buf + tA * 136 + kt * 32 + quad * 8);
    WBAR();

    // ---- FFN: 4 chunks of 128 hidden, wave-local h staging in s_buf ----
    f32x4 zacc[8];
    #pragma unroll
    for (int nt = 0; nt < 8; ++nt) zacc[nt] = f32x4{0.f, 0.f, 0.f, 0.f};

    for (int ch = 0; ch < 4; ++ch) {
        #pragma unroll
        for (int ntl = 0; ntl < 8; ++ntl) {
            f32x4 c = {0.f, 0.f, 0.f, 0.f};
            #pragma unroll
            for (int kt = 0; kt < 4; ++kt) {
                half8 bf = *(const half8*)(W1p + (((ch * 8 + ntl) * 4 + kt) * 64 + lane) * 8);
                c = __builtin_amdgcn_mfma_f32_16x16x32_f16(xfrag[kt], bf, c, 0, 0, 0);
            }
            float bv = bv1[ch * 128 + ntl * 16 + l16];
            #pragma unroll
            for (int r = 0; r < 4; ++r) {
                float hx = c[r] + bv;
                // mish(x) = x*(t^2-1)/(t^2+1), t = 1+e^x  (== x*tanh(softplus(x)))
                float e = __expf(fminf(hx, 30.f));
                float t = 1.f + e, t2 = t * t;
                float mish = hx * (t2 - 1.f) * __builtin_amdgcn_rcpf(t2 + 1.f);
                s_buf[(w * 16 + quad * 4 + r) * 136 + ntl * 16 + l16] = (_Float16)mish;
            }
        }
        WBAR();
        half8 hfrag[4];
        #pragma unroll
        for (int kt = 0; kt < 4; ++kt)
            hfrag[kt] = *(const half8*)(s_buf + tA * 136 + kt * 32 + quad * 8);
        WBAR();
        #pragma unroll
        for (int nt = 0; nt < 8; ++nt) {
            #pragma unroll
            for (int ktl = 0; ktl < 4; ++ktl) {
                half8 bf = *(const half8*)(W2p + ((nt * 16 + ch * 4 + ktl) * 64 + lane) * 8);
                zacc[nt] = __builtin_amdgcn_mfma_f32_16x16x32_f16(hfrag[ktl], bf, zacc[nt], 0, 0, 0);
            }
        }
        WBAR();   // order next chunk's s_buf writes after this chunk's reads
    }

    // ---- out = z + b2 + y ----
    #pragma unroll
    for (int r = 0; r < 4; ++r) {
        float* orow = ob + (tok0 + w * 16 + quad * 4 + r) * (long)ldo;
        #pragma unroll
        for (int nt = 0; nt < 8; ++nt)
            orow[nt * 16 + l16] = zacc[nt][r] + bb2[nt] + y[nt][r];
    }
}

// ---------------------------------------------------------------------------
// enc0 = concat(e1, e2) @ WL2 + bL2
// ---------------------------------------------------------------------------
__global__ __launch_bounds__(256) void enc_combine(
    const float* __restrict__ e1, const float* __restrict__ e2,
    float* __restrict__ outp,
    const float* __restrict__ W, const float* __restrict__ bias)
{
    __shared__ float sc[32 * 256];
    const int tid = threadIdx.x;
    const long tok0 = (long)blockIdx.x * 32;
    #pragma unroll
    for (int r = 0; r < 4; ++r) {
        int u = tid + r * 256;
        int tok = u >> 5, c4 = u & 31;
        *(float4*)(sc + tok * 256 + c4 * 4)       = *(const float4*)(e1 + (tok0 + tok) * 128 + c4 * 4);
        *(float4*)(sc + tok * 256 + 128 + c4 * 4) = *(const float4*)(e2 + (tok0 + tok) * 128 + c4 * 4);
    }
    __syncthreads();
    const int j = tid & 63, tg = tid >> 6;
    float a0[8], a1[8];
    #pragma unroll
    for (int t = 0; t < 8; ++t) { a0[t] = 0.f; a1[t] = 0.f; }
    for (int i = 0; i < 256; i += 4) {
        float w0[4], w1[4];
        #pragma unroll
        for (int u = 0; u < 4; ++u) {
            w0[u] = W[(long)(i + u) * 128 + j];
            w1[u] = W[(long)(i + u) * 128 + j + 64];
        }
        #pragma unroll
        for (int t = 0; t < 8; ++t) {
            float4 xv = *(const float4*)(sc + (tg * 8 + t) * 256 + i);
            a0[t] += xv.x * w0[0] + xv.y * w0[1] + xv.z * w0[2] + xv.w * w0[3];
            a1[t] += xv.x * w1[0] + xv.y * w1[1] + xv.z * w1[2] + xv.w * w1[3];
        }
    }
    float b0 = bias[j], b1 = bias[j + 64];
    #pragma unroll
    for (int t = 0; t < 8; ++t) {
        int tok = tg * 8 + t;
        outp[(tok0 + tok) * 128 + j]      = a0[t] + b0;
        outp[(tok0 + tok) * 128 + j + 64] = a1[t] + b1;
    }
}

// ---------------------------------------------------------------------------
extern "C" void kernel_launch(void* const* d_in, const int* in_sizes, int n_in,
                              void* d_out, int out_size, void* d_ws, size_t ws_size,
                              hipStream_t stream)
{
    const float* src  = (const float*)d_in[0];
    const float* ln1g = (const float*)d_in[2];
    const float* ln1b = (const float*)d_in[3];
    const float* Wq   = (const float*)d_in[4];
    const float* Wk   = (const float*)d_in[5];
    const float* Wv   = (const float*)d_in[6];
    const float* Wfc  = (const float*)d_in[7];
    const float* ln2g = (const float*)d_in[8];
    const float* ln2b = (const float*)d_in[9];
    const float* W1   = (const float*)d_in[10];
    const float* b1   = (const float*)d_in[11];
    const float* W2   = (const float*)d_in[12];
    const float* b2   = (const float*)d_in[13];
    const float* WL2  = (const float*)d_in[14];
    const float* bL2  = (const float*)d_in[15];
    float* out = (float*)d_out;

    const long TOKS = (long)NTOK * 128;
    float* ws  = (float*)d_ws;
    float* XE1 = ws;
    float* XE2 = ws + TOKS;
    _Float16* V8 = (_Float16*)(ws + 2 * TOKS);          // 4*NTOK*64 fp16
    float* ATT = (float*)(V8 + 4L * NTOK * 64);         // 4*B*1024 f32
    _Float16* WPfc = (_Float16*)(ATT + 4 * B_ * 1024);  // 4*16384
    _Float16* WP1  = WPfc + 4L * 16384;                 // 4*65536
    _Float16* WP2  = WP1 + 4L * 65536;                  // 4*65536
    if (ws_size < 205000000ULL) return;

    float* m1b  = out + TOKS;
    float* m2b  = out + 2 * TOKS;
    float* encb = out;
    const float* bufs[4] = { m1b, m2b, XE1, XE2 };

    // ---- pack weights to fp16 B-fragment order (d_ws re-poisoned per call) ----
    pack_b<<<dim3(64, 4),  dim3(256), 0, stream>>>(Wfc, WPfc, 128, 128);
    pack_b<<<dim3(256, 4), dim3(256), 0, stream>>>(W1,  WP1,  128, 512);
    pack_b<<<dim3(256, 4), dim3(256), 0, stream>>>(W2,  WP2,  512, 128);

    // ---- stacked phase: streams {m1, m2, e1, e2} ----
    for (int l = 0; l < 4; ++l) {
        hipMemsetAsync(ATT, 0, 4 * B_ * 1024 * sizeof(float), stream);
        P4 qp, kp, op;
        int ldq, ldk;
        if (l == 0) {
            qp = P4{{ src, src + 128, src + 128, src }};  ldq = 256;
            kp = P4{{ src, src + 128, src, src + 128 }};  ldk = 256;
        } else {
            qp = P4{{ bufs[0], bufs[1], bufs[2], bufs[3] }}; ldq = 128;
            kp = qp; ldk = 128;
        }
        op = P4{{ bufs[0], bufs[1], bufs[2], bufs[3] }};
        const long wo = (long)l * 128 * 128;
        enc_qkv_attn<<<dim3(4 * 2048), dim3(256), 0, stream>>>(
            qp, ldq, kp, ldk, V8, ATT,
            Wq + wo, Wk + wo, Wv + wo, ln1g + l * 128, ln1b + l * 128);
        enc_post_mfma<<<dim3(4 * 2048), dim3(256), 0, stream>>>(
            qp, ldq, op, 128, V8, ATT,
            WPfc + (long)l * 16384, ln2g + l * 128, ln2b + l * 128,
            WP1 + (long)l * 65536, b1 + l * 512,
            WP2 + (long)l * 65536, b2 + l * 128);
    }

    // ---- enc = concat(e1,e2) @ WL2 + bL2 ----
    enc_combine<<<dim3(4096), dim3(256), 0, stream>>>(XE1, XE2, encb, WL2, bL2);

    // ---- enc phase ----
    for (int l = 0; l < 4; ++l) {
        hipMemsetAsync(ATT, 0, B_ * 1024 * sizeof(float), stream);
        P4 p = P4{{ encb, encb, encb, encb }};
        const long wo = (long)l * 128 * 128;
        enc_qkv_attn<<<dim3(2048), dim3(256), 0, stream>>>(
            p, 128, p, 128, V8, ATT,
            Wq + wo, Wk + wo, Wv + wo, ln1g + l * 128, ln1b + l * 128);
        enc_post_mfma<<<dim3(2048), dim3(256), 0, stream>>>(
            p, 128, p, 128, V8, ATT,
            WPfc + (long)l * 16384, ln2g + l * 128, ln2b + l * 128,
            WP1 + (long)l * 65536, b1 + l * 512,
            WP2 + (long)l * 65536, b2 + l * 128);
    }
}

// Round 3
// 8764.141 us; speedup vs baseline: 1.1675x; 1.1675x over previous
//
#include <hip/hip_runtime.h>
#include <math.h>

// Problem constants (from reference)
#define H_    8
#define DK_   16
#define DM_   128
#define DI_   512
#define B_    64
#define S_    2048
#define NTOK  131072          // B_*S_
#define EPS_  1e-6f
#define INV_TEMP 0.5f         // TEMP = 0.5*sqrt(16) = 2.0

typedef __attribute__((ext_vector_type(8))) _Float16 half8;
typedef __attribute__((ext_vector_type(4))) _Float16 half4;
typedef __attribute__((ext_vector_type(4))) float f32x4;

struct P4 { const float* p[4]; };

// ---------------------------------------------------------------------------
// Pack a K x N f32 weight (row-major) into fp16 fragment order for
// mfma_f32_16x16x32_f16: flat[((nt*(K/32)+kt)*64 + lane)*8 + j] =
//   W[kt*32 + (lane>>4)*8 + j][nt*16 + (lane&15)].  blockIdx.y = layer.
// This layout is BOTH the B-frag of W and the A-frag of W^T (identical lane
// mapping), so swapped-operand MFMA (transposed output) needs no new pack.
// ---------------------------------------------------------------------------
__global__ __launch_bounds__(256) void pack_b(
    const float* __restrict__ W, _Float16* __restrict__ out, int K, int N)
{
    long base = (long)blockIdx.y * K * N;
    int idx = blockIdx.x * 256 + threadIdx.x;
    if (idx >= K * N) return;
    int j = idx & 7;
    int lane = (idx >> 3) & 63;
    int t = idx >> 9;                 // tile = nt*(K/32)+kt
    int KT = K >> 5;
    int nt = t / KT, kt = t - nt * KT;
    int k = kt * 32 + (lane >> 4) * 8 + j;
    int n = nt * 16 + (lane & 15);
    out[base + idx] = (_Float16)W[base + (long)k * N + n];
}

// ---------------------------------------------------------------------------
// Kernel A: per 64-token tile, 4 waves, each wave owns 16 token rows.
// ALL phases (load, folded K/V proj, LN1 via 4-lane shfl reduce, Q proj,
// score partials) are wave-local -> single __syncthreads before the
// cross-wave partial-score reduction + atomicAdd.
// ---------------------------------------------------------------------------
__global__ __launch_bounds__(256) void enc_qkv_attn(
    P4 qp, int ldq, P4 kp, int ldk,
    _Float16* __restrict__ v8, float* __restrict__ att,
    const float* __restrict__ Wq, const float* __restrict__ Wk,
    const float* __restrict__ Wv,
    const float* __restrict__ lng, const float* __restrict__ lnb)
{
    __shared__ float sx[64 * 128];
    __shared__ float sk8[64 * 64];
    __shared__ float spart[4 * 128 * 8];

    const int tid  = threadIdx.x;
    const int w    = tid >> 6;          // wave 0..3
    const int lane = tid & 63;
    const int bx   = blockIdx.x;
    const int s    = bx >> 11;
    const int blk  = bx & 2047;
    const long tok0 = (long)blk * 64;
    const int b = blk >> 5;
    const int tw0 = w * 16;             // wave-owned rows tw0..tw0+15

    const float* qb = qp.p[s];
    const float* kb = kp.p[s];
    _Float16* v8s = v8 + (long)s * ((long)NTOK * 64) + tok0 * 64;
    float* atts = att + (long)s * (B_ * 1024) + (long)b * 1024;

    // ---- phase 1: wave-local load of this wave's 16 k-input rows ----
    #pragma unroll
    for (int r = 0; r < 8; ++r) {
        int u = r * 64 + lane;
        int tok = tw0 + (u >> 5), c4 = u & 31;
        float4 v = *(const float4*)(kb + (tok0 + tok) * (long)ldk + c4 * 4);
        *(float4*)(sx + tok * 128 + c4 * 4) = v;
    }
    __builtin_amdgcn_wave_barrier();

    // ---- phase 2: folded K/V projection (pair-mean folded into weights) ----
    {
        const int j = lane;
        float ka[16], va[16];
        #pragma unroll
        for (int t = 0; t < 16; ++t) { ka[t] = 0.f; va[t] = 0.f; }
        for (int i = 0; i < 128; i += 4) {
            float wk[4], wv[4];
            #pragma unroll
            for (int u = 0; u < 4; ++u) {
                float2 a = *(const float2*)(Wk + (long)(i + u) * 128 + 2 * j);
                float2 c = *(const float2*)(Wv + (long)(i + u) * 128 + 2 * j);
                wk[u] = 0.5f * (a.x + a.y);
                wv[u] = 0.5f * (c.x + c.y);
            }
            #pragma unroll
            for (int t = 0; t < 16; ++t) {
                float4 xv = *(const float4*)(sx + (tw0 + t) * 128 + i);
                ka[t] += xv.x * wk[0] + xv.y * wk[1] + xv.z * wk[2] + xv.w * wk[3];
                va[t] += xv.x * wv[0] + xv.y * wv[1] + xv.z * wv[2] + xv.w * wv[3];
            }
        }
        #pragma unroll
        for (int t = 0; t < 16; ++t) {
            int tok = tw0 + t;
            sk8[tok * 64 + j] = ka[t];
            v8s[(long)tok * 64 + j] = (_Float16)va[t];
        }
    }
    __builtin_amdgcn_wave_barrier();

    // ---- phase 3: reload q rows if q-input differs ----
    if (qb != kb || ldq != ldk) {
        #pragma unroll
        for (int r = 0; r < 8; ++r) {
            int u = r * 64 + lane;
            int tok = tw0 + (u >> 5), c4 = u & 31;
            float4 v = *(const float4*)(qb + (tok0 + tok) * (long)ldq + c4 * 4);
            *(float4*)(sx + tok * 128 + c4 * 4) = v;
        }
        __builtin_amdgcn_wave_barrier();
    }

    // ---- phase 4: LN1, wave-local (4 lanes per token, shfl_xor reduce) ----
    {
        const int t = lane >> 2, part = lane & 3;
        float* xr = sx + (tw0 + t) * 128 + part * 32;
        float sum = 0.f;
        #pragma unroll
        for (int i = 0; i < 32; i += 4) {
            float4 v = *(const float4*)(xr + i);
            sum += v.x + v.y + v.z + v.w;
        }
        sum += __shfl_xor(sum, 1); sum += __shfl_xor(sum, 2);
        const float mu = sum * (1.f / 128.f);
        float ss = 0.f;
        #pragma unroll
        for (int i = 0; i < 32; i += 4) {
            float4 v = *(const float4*)(xr + i);
            float d0 = v.x - mu, d1 = v.y - mu, d2 = v.z - mu, d3 = v.w - mu;
            ss += d0 * d0 + d1 * d1 + d2 * d2 + d3 * d3;
        }
        ss += __shfl_xor(ss, 1); ss += __shfl_xor(ss, 2);
        const float rs = rsqrtf(ss * (1.f / 128.f) + EPS_);
        #pragma unroll
        for (int i = 0; i < 32; i += 4) {
            float4 v  = *(const float4*)(xr + i);
            float4 g  = *(const float4*)(lng + part * 32 + i);
            float4 bb = *(const float4*)(lnb + part * 32 + i);
            v.x = (v.x - mu) * rs * g.x + bb.x;
            v.y = (v.y - mu) * rs * g.y + bb.y;
            v.z = (v.z - mu) * rs * g.z + bb.z;
            v.w = (v.w - mu) * rs * g.w + bb.w;
            *(float4*)(xr + i) = v;
        }
    }
    __builtin_amdgcn_wave_barrier();

    // ---- phase 5: Q proj + score partials (wave-local rows) ----
    {
        const int j = lane;
        float qa0[16], qa1[16];
        #pragma unroll
        for (int t = 0; t < 16; ++t) { qa0[t] = 0.f; qa1[t] = 0.f; }
        for (int i = 0; i < 128; i += 4) {
            float w0[4], w1[4];
            #pragma unroll
            for (int u = 0; u < 4; ++u) {
                w0[u] = Wq[(long)(i + u) * 128 + j];
                w1[u] = Wq[(long)(i + u) * 128 + j + 64];
            }
            #pragma unroll
            for (int t = 0; t < 16; ++t) {
                float4 xv = *(const float4*)(sx + (tw0 + t) * 128 + i);
                qa0[t] += xv.x * w0[0] + xv.y * w0[1] + xv.z * w0[2] + xv.w * w0[3];
                qa1[t] += xv.x * w1[0] + xv.y * w1[1] + xv.z * w1[2] + xv.w * w1[3];
            }
        }
        #pragma unroll
        for (int fi = 0; fi < 2; ++fi) {
            int f = j + fi * 64;
            int h = f >> 4;
            float p[8];
            #pragma unroll
            for (int e = 0; e < 8; ++e) p[e] = 0.f;
            #pragma unroll
            for (int t = 0; t < 16; ++t) {
                int tok = tw0 + t;
                float4 k0 = *(const float4*)(sk8 + tok * 64 + h * 8);
                float4 k1 = *(const float4*)(sk8 + tok * 64 + h * 8 + 4);
                float q = fi ? qa1[t] : qa0[t];
                p[0] += q * k0.x; p[1] += q * k0.y; p[2] += q * k0.z; p[3] += q * k0.w;
                p[4] += q * k1.x; p[5] += q * k1.y; p[6] += q * k1.z; p[7] += q * k1.w;
            }
            #pragma unroll
            for (int e = 0; e < 8; ++e) spart[(w * 128 + f) * 8 + e] = p[e];
        }
    }
    __syncthreads();    // the ONLY block-wide barrier: cross-wave reduce
    for (int idx = tid; idx < 1024; idx += 256) {
        float v = spart[idx] + spart[1024 + idx] + spart[2048 + idx] + spart[3072 + idx];
        atomicAdd(atts + idx, v);
    }
}

// ---------------------------------------------------------------------------
// Kernel C (MFMA, fp16, SWAPPED operands): per 64-token tile, 4 waves,
// wave = 16 tokens (token = w*16 + (lane&15)).  All GEMMs computed as
// D^T = W^T(as A) x X^T(as B) -> lane holds [feature=quad*4+r][token=l16].
// The packed weight buffers serve directly as A-frags of W^T (same lane
// mapping as B-frags of W).  Benefits vs un-swapped:
//   - residual loads / final stores are float4 (8 ops vs 32 scalars)
//   - LN2 = in-lane 32-sum + shfl_xor(16,32)
//   - FFN h staging in [token][hid] layout: 8x ds_write_b64 + 4x ds_read_b128
//     per chunk, wave-local rows -> NO barriers in the chunk loop, so the
//     compiler pipelines chunk ch+1 GEMM1 under chunk ch GEMM2.
// Single __syncthreads (s_att).  LDS = 4KB + 17.4KB.
// ---------------------------------------------------------------------------
__global__ __launch_bounds__(256) void enc_post_mfma(
    P4 xp, int ldx, P4 op, int ldo,
    const _Float16* __restrict__ v8, const float* __restrict__ att,
    const _Float16* __restrict__ Wfcp,
    const float* __restrict__ lng, const float* __restrict__ lnb,
    const _Float16* __restrict__ W1p, const float* __restrict__ bv1,
    const _Float16* __restrict__ W2p, const float* __restrict__ bv2)
{
    __shared__ float s_att[1024];
    __shared__ _Float16 s_x[64 * 136];  // [token][128 + 8 pad] halves

    const int tid  = threadIdx.x;
    const int w    = tid >> 6;          // wave 0..3
    const int lane = tid & 63;
    const int quad = lane >> 4, l16 = lane & 15;
    const int bx   = blockIdx.x;
    const int s    = bx >> 11;          // 2048 blocks per stream
    const int blk  = bx & 2047;
    const long tok0 = (long)blk * 64;
    const int b = blk >> 5;

    const float* xb = xp.p[s];
    float* ob = (float*)op.p[s];
    const _Float16* v8s = v8 + (long)s * ((long)NTOK * 64) + tok0 * 64;
    const float* atts = att + (long)s * (B_ * 1024) + (long)b * 1024;

    const int trow = w * 16 + l16;      // this lane's token row (0..63)

    if (tid < 128) {                    // softmax rows h*16+d
        float sc[8];
        #pragma unroll
        for (int e = 0; e < 8; ++e) sc[e] = atts[tid * 8 + e] * INV_TEMP;
        float m = sc[0];
        #pragma unroll
        for (int e = 1; e < 8; ++e) m = fmaxf(m, sc[e]);
        float sum = 0.f;
        #pragma unroll
        for (int e = 0; e < 8; ++e) { sc[e] = expf(sc[e] - m); sum += sc[e]; }
        float inv = 1.f / sum;
        #pragma unroll
        for (int e = 0; e < 8; ++e) s_att[tid * 8 + e] = sc[e] * inv;
    }
    __syncthreads();                    // the ONLY block-wide barrier

    // ---- attn apply -> fragments. Lane token trow, features kt*32+quad*8+j.
    // f = d*8+h with h=j, d=kt*4+quad; att row = h*16+d; v feature = h*8+e.
    half8 afrag[4];
    {
        const _Float16* vrow = v8s + (long)trow * 64;
        float ao[4][8];
        #pragma unroll
        for (int j = 0; j < 8; ++j) {
            half8 hv = *(const half8*)(vrow + j * 8);
            float v0 = (float)hv[0], v1 = (float)hv[1], v2 = (float)hv[2], v3 = (float)hv[3];
            float v4 = (float)hv[4], v5 = (float)hv[5], v6 = (float)hv[6], v7 = (float)hv[7];
            #pragma unroll
            for (int kt = 0; kt < 4; ++kt) {
                const float* ar = s_att + (j * 16 + kt * 4 + quad) * 8;
                float4 a0 = *(const float4*)ar;
                float4 a1 = *(const float4*)(ar + 4);
                ao[kt][j] = a0.x * v0 + a0.y * v1 + a0.z * v2 + a0.w * v3
                          + a1.x * v4 + a1.y * v5 + a1.z * v6 + a1.w * v7;
            }
        }
        #pragma unroll
        for (int kt = 0; kt < 4; ++kt)
            #pragma unroll
            for (int j = 0; j < 8; ++j)
                afrag[kt][j] = (_Float16)ao[kt][j];
    }

    // ---- Wfc swapped: yT[nt] : lane holds y^T[feat=nt*16+quad*4+r][tok=trow]
    f32x4 yacc[8];
    #pragma unroll
    for (int nt = 0; nt < 8; ++nt) {
        f32x4 c = {0.f, 0.f, 0.f, 0.f};
        #pragma unroll
        for (int kt = 0; kt < 4; ++kt) {
            half8 wf = *(const half8*)(Wfcp + ((nt * 4 + kt) * 64 + lane) * 8);
            c = __builtin_amdgcn_mfma_f32_16x16x32_f16(wf, afrag[kt], c, 0, 0, 0);
        }
        yacc[nt] = c;
    }

    // ---- residual (float4 loads): y[nt][r] feature = nt*16+quad*4+r ----
    float y[8][4];
    {
        const float* xrow = xb + (tok0 + trow) * (long)ldx;
        #pragma unroll
        for (int nt = 0; nt < 8; ++nt) {
            f32x4 xv = *(const f32x4*)(xrow + nt * 16 + quad * 4);
            #pragma unroll
            for (int r = 0; r < 4; ++r) y[nt][r] = yacc[nt][r] + xv[r];
        }
    }

    // ---- LN2: in-lane 32-sum + quad butterfly (xor 16, 32) ----
    float mu, rs;
    {
        float sm = 0.f;
        #pragma unroll
        for (int nt = 0; nt < 8; ++nt)
            #pragma unroll
            for (int r = 0; r < 4; ++r) sm += y[nt][r];
        sm += __shfl_xor(sm, 16); sm += __shfl_xor(sm, 32);
        mu = sm * (1.f / 128.f);
        float ss = 0.f;
        #pragma unroll
        for (int nt = 0; nt < 8; ++nt)
            #pragma unroll
            for (int r = 0; r < 4; ++r) { float d = y[nt][r] - mu; ss += d * d; }
        ss += __shfl_xor(ss, 16); ss += __shfl_xor(ss, 32);
        rs = rsqrtf(ss * (1.f / 128.f) + EPS_);
    }

    // ---- xn -> LDS [token][feat] (b64 writes, wave-local rows) ----
    #pragma unroll
    for (int nt = 0; nt < 8; ++nt) {
        f32x4 g  = *(const f32x4*)(lng + nt * 16 + quad * 4);
        f32x4 bb = *(const f32x4*)(lnb + nt * 16 + quad * 4);
        half4 hv;
        #pragma unroll
        for (int r = 0; r < 4; ++r)
            hv[r] = (_Float16)((y[nt][r] - mu) * rs * g[r] + bb[r]);
        *(half4*)(s_x + trow * 136 + nt * 16 + quad * 4) = hv;
    }
    // same-wave DS ordering: rows trow are wave-local, reads below depend.
    half8 xfrag[4];
    #pragma unroll
    for (int kt = 0; kt < 4; ++kt)
        xfrag[kt] = *(const half8*)(s_x + trow * 136 + kt * 32 + quad * 8);

    // ---- FFN: 4 chunks of 128 hidden, all swapped, barrier-free ----
    f32x4 zacc[8];
    #pragma unroll
    for (int nt = 0; nt < 8; ++nt) zacc[nt] = f32x4{0.f, 0.f, 0.f, 0.f};

    for (int ch = 0; ch < 4; ++ch) {
        // GEMM1 swapped: hT tile tl: lane holds h^T[hid=tl*16+quad*4+r][trow]
        #pragma unroll
        for (int tl = 0; tl < 8; ++tl) {
            f32x4 c1 = {0.f, 0.f, 0.f, 0.f};
            #pragma unroll
            for (int kt = 0; kt < 4; ++kt) {
                half8 wf = *(const half8*)(W1p + (((ch * 8 + tl) * 4 + kt) * 64 + lane) * 8);
                c1 = __builtin_amdgcn_mfma_f32_16x16x32_f16(wf, xfrag[kt], c1, 0, 0, 0);
            }
            f32x4 bv = *(const f32x4*)(bv1 + ch * 128 + tl * 16 + quad * 4);
            half4 hh;
            #pragma unroll
            for (int r = 0; r < 4; ++r) {
                float hx = c1[r] + bv[r];
                // mish(x) = x*(t^2-1)/(t^2+1), t = 1+e^x
                float e = __expf(fminf(hx, 30.f));
                float t = 1.f + e, t2 = t * t;
                hh[r] = (_Float16)(hx * (t2 - 1.f) * __builtin_amdgcn_rcpf(t2 + 1.f));
            }
            *(half4*)(s_x + trow * 136 + tl * 16 + quad * 4) = hh;
        }
        half8 hfrag[4];
        #pragma unroll
        for (int ks = 0; ks < 4; ++ks)
            hfrag[ks] = *(const half8*)(s_x + trow * 136 + ks * 32 + quad * 8);
        // GEMM2 swapped: zacc[nt] += W2^T x h^T
        #pragma unroll
        for (int nt = 0; nt < 8; ++nt) {
            #pragma unroll
            for (int ks = 0; ks < 4; ++ks) {
                half8 wf = *(const half8*)(W2p + ((nt * 16 + ch * 4 + ks) * 64 + lane) * 8);
                zacc[nt] = __builtin_amdgcn_mfma_f32_16x16x32_f16(wf, hfrag[ks], zacc[nt], 0, 0, 0);
            }
        }
    }

    // ---- out = z + b2 + y  (float4 stores) ----
    {
        float* orow = ob + (tok0 + trow) * (long)ldo;
        #pragma unroll
        for (int nt = 0; nt < 8; ++nt) {
            f32x4 b2v = *(const f32x4*)(bv2 + nt * 16 + quad * 4);
            f32x4 o;
            #pragma unroll
            for (int r = 0; r < 4; ++r) o[r] = zacc[nt][r] + b2v[r] + y[nt][r];
            *(f32x4*)(orow + nt * 16 + quad * 4) = o;
        }
    }
}

// ---------------------------------------------------------------------------
// enc0 = concat(e1, e2) @ WL2 + bL2
// ---------------------------------------------------------------------------
__global__ __launch_bounds__(256) void enc_combine(
    const float* __restrict__ e1, const float* __restrict__ e2,
    float* __restrict__ outp,
    const float* __restrict__ W, const float* __restrict__ bias)
{
    __shared__ float sc[32 * 256];
    const int tid = threadIdx.x;
    const long tok0 = (long)blockIdx.x * 32;
    #pragma unroll
    for (int r = 0; r < 4; ++r) {
        int u = tid + r * 256;
        int tok = u >> 5, c4 = u & 31;
        *(float4*)(sc + tok * 256 + c4 * 4)       = *(const float4*)(e1 + (tok0 + tok) * 128 + c4 * 4);
        *(float4*)(sc + tok * 256 + 128 + c4 * 4) = *(const float4*)(e2 + (tok0 + tok) * 128 + c4 * 4);
    }
    __syncthreads();
    const int j = tid & 63, tg = tid >> 6;
    float a0[8], a1[8];
    #pragma unroll
    for (int t = 0; t < 8; ++t) { a0[t] = 0.f; a1[t] = 0.f; }
    for (int i = 0; i < 256; i += 4) {
        float w0[4], w1[4];
        #pragma unroll
        for (int u = 0; u < 4; ++u) {
            w0[u] = W[(long)(i + u) * 128 + j];
            w1[u] = W[(long)(i + u) * 128 + j + 64];
        }
        #pragma unroll
        for (int t = 0; t < 8; ++t) {
            float4 xv = *(const float4*)(sc + (tg * 8 + t) * 256 + i);
            a0[t] += xv.x * w0[0] + xv.y * w0[1] + xv.z * w0[2] + xv.w * w0[3];
            a1[t] += xv.x * w1[0] + xv.y * w1[1] + xv.z * w1[2] + xv.w * w1[3];
        }
    }
    float b0 = bias[j], b1 = bias[j + 64];
    #pragma unroll
    for (int t = 0; t < 8; ++t) {
        int tok = tg * 8 + t;
        outp[(tok0 + tok) * 128 + j]      = a0[t] + b0;
        outp[(tok0 + tok) * 128 + j + 64] = a1[t] + b1;
    }
}

// ---------------------------------------------------------------------------
extern "C" void kernel_launch(void* const* d_in, const int* in_sizes, int n_in,
                              void* d_out, int out_size, void* d_ws, size_t ws_size,
                              hipStream_t stream)
{
    const float* src  = (const float*)d_in[0];
    const float* ln1g = (const float*)d_in[2];
    const float* ln1b = (const float*)d_in[3];
    const float* Wq   = (const float*)d_in[4];
    const float* Wk   = (const float*)d_in[5];
    const float* Wv   = (const float*)d_in[6];
    const float* Wfc  = (const float*)d_in[7];
    const float* ln2g = (const float*)d_in[8];
    const float* ln2b = (const float*)d_in[9];
    const float* W1   = (const float*)d_in[10];
    const float* b1   = (const float*)d_in[11];
    const float* W2   = (const float*)d_in[12];
    const float* b2   = (const float*)d_in[13];
    const float* WL2  = (const float*)d_in[14];
    const float* bL2  = (const float*)d_in[15];
    float* out = (float*)d_out;

    const long TOKS = (long)NTOK * 128;
    float* ws  = (float*)d_ws;
    float* XE1 = ws;
    float* XE2 = ws + TOKS;
    _Float16* V8 = (_Float16*)(ws + 2 * TOKS);          // 4*NTOK*64 fp16
    float* ATT = (float*)(V8 + 4L * NTOK * 64);         // 4*B*1024 f32
    _Float16* WPfc = (_Float16*)(ATT + 4 * B_ * 1024);  // 4*16384
    _Float16* WP1  = WPfc + 4L * 16384;                 // 4*65536
    _Float16* WP2  = WP1 + 4L * 65536;                  // 4*65536
    if (ws_size < 205000000ULL) return;

    float* m1b  = out + TOKS;
    float* m2b  = out + 2 * TOKS;
    float* encb = out;
    const float* bufs[4] = { m1b, m2b, XE1, XE2 };

    // ---- pack weights to fp16 fragment order (d_ws re-poisoned per call) ----
    pack_b<<<dim3(64, 4),  dim3(256), 0, stream>>>(Wfc, WPfc, 128, 128);
    pack_b<<<dim3(256, 4), dim3(256), 0, stream>>>(W1,  WP1,  128, 512);
    pack_b<<<dim3(256, 4), dim3(256), 0, stream>>>(W2,  WP2,  512, 128);

    // ---- stacked phase: streams {m1, m2, e1, e2} ----
    for (int l = 0; l < 4; ++l) {
        hipMemsetAsync(ATT, 0, 4 * B_ * 1024 * sizeof(float), stream);
        P4 qp, kp, op;
        int ldq, ldk;
        if (l == 0) {
            qp = P4{{ src, src + 128, src + 128, src }};  ldq = 256;
            kp = P4{{ src, src + 128, src, src + 128 }};  ldk = 256;
        } else {
            qp = P4{{ bufs[0], bufs[1], bufs[2], bufs[3] }}; ldq = 128;
            kp = qp; ldk = 128;
        }
        op = P4{{ bufs[0], bufs[1], bufs[2], bufs[3] }};
        const long wo = (long)l * 128 * 128;
        enc_qkv_attn<<<dim3(4 * 2048), dim3(256), 0, stream>>>(
            qp, ldq, kp, ldk, V8, ATT,
            Wq + wo, Wk + wo, Wv + wo, ln1g + l * 128, ln1b + l * 128);
        enc_post_mfma<<<dim3(4 * 2048), dim3(256), 0, stream>>>(
            qp, ldq, op, 128, V8, ATT,
            WPfc + (long)l * 16384, ln2g + l * 128, ln2b + l * 128,
            WP1 + (long)l * 65536, b1 + l * 512,
            WP2 + (long)l * 65536, b2 + l * 128);
    }

    // ---- enc = concat(e1,e2) @ WL2 + bL2 ----
    enc_combine<<<dim3(4096), dim3(256), 0, stream>>>(XE1, XE2, encb, WL2, bL2);

    // ---- enc phase ----
    for (int l = 0; l < 4; ++l) {
        hipMemsetAsync(ATT, 0, B_ * 1024 * sizeof(float), stream);
        P4 p = P4{{ encb, encb, encb, encb }};
        const long wo = (long)l * 128 * 128;
        enc_qkv_attn<<<dim3(2048), dim3(256), 0, stream>>>(
            p, 128, p, 128, V8, ATT,
            Wq + wo, Wk + wo, Wv + wo, ln1g + l * 128, ln1b + l * 128);
        enc_post_mfma<<<dim3(2048), dim3(256), 0, stream>>>(
            p, 128, p, 128, V8, ATT,
            WPfc + (long)l * 16384, ln2g + l * 128, ln2b + l * 128,
            WP1 + (long)l * 65536, b1 + l * 512,
            WP2 + (long)l * 65536, b2 + l * 128);
    }
}

// Round 6
// 7637.133 us; speedup vs baseline: 1.3398x; 1.1476x over previous
//
#include <hip/hip_runtime.h>
#include <math.h>

// Problem constants (from reference)
#define H_    8
#define DK_   16
#define DM_   128
#define DI_   512
#define B_    64
#define S_    2048
#define NTOK  131072          // B_*S_
#define EPS_  1e-6f
#define INV_TEMP 0.5f         // TEMP = 0.5*sqrt(16) = 2.0

typedef __attribute__((ext_vector_type(8))) _Float16 half8;
typedef __attribute__((ext_vector_type(4))) _Float16 half4;
typedef __attribute__((ext_vector_type(4))) float f32x4;

struct P4 { const float* p[4]; };

// ---------------------------------------------------------------------------
// Pack a K x N f32 weight (row-major) into fp16 fragment order for
// mfma_f32_16x16x32_f16: flat[((nt*(K/32)+kt)*64 + lane)*8 + j] =
//   W[kt*32 + (lane>>4)*8 + j][nt*16 + (lane&15)].  blockIdx.y = layer.
// This layout is BOTH the B-frag of W and the A-frag of W^T (identical lane
// mapping), so swapped-operand MFMA (transposed output) needs no new pack.
// ---------------------------------------------------------------------------
__global__ __launch_bounds__(256) void pack_b(
    const float* __restrict__ W, _Float16* __restrict__ out, int K, int N)
{
    long base = (long)blockIdx.y * K * N;
    int idx = blockIdx.x * 256 + threadIdx.x;
    if (idx >= K * N) return;
    int j = idx & 7;
    int lane = (idx >> 3) & 63;
    int t = idx >> 9;                 // tile = nt*(K/32)+kt
    int KT = K >> 5;
    int nt = t / KT, kt = t - nt * KT;
    int k = kt * 32 + (lane >> 4) * 8 + j;
    int n = nt * 16 + (lane & 15);
    out[base + idx] = (_Float16)W[base + (long)k * N + n];
}

// ---------------------------------------------------------------------------
// Kernel A: per 64-token tile, 4 waves, each wave owns 16 token rows.
// (unchanged from round 3)
// ---------------------------------------------------------------------------
__global__ __launch_bounds__(256) void enc_qkv_attn(
    P4 qp, int ldq, P4 kp, int ldk,
    _Float16* __restrict__ v8, float* __restrict__ att,
    const float* __restrict__ Wq, const float* __restrict__ Wk,
    const float* __restrict__ Wv,
    const float* __restrict__ lng, const float* __restrict__ lnb)
{
    __shared__ float sx[64 * 128];
    __shared__ float sk8[64 * 64];
    __shared__ float spart[4 * 128 * 8];

    const int tid  = threadIdx.x;
    const int w    = tid >> 6;          // wave 0..3
    const int lane = tid & 63;
    const int bx   = blockIdx.x;
    const int s    = bx >> 11;
    const int blk  = bx & 2047;
    const long tok0 = (long)blk * 64;
    const int b = blk >> 5;
    const int tw0 = w * 16;             // wave-owned rows tw0..tw0+15

    const float* qb = qp.p[s];
    const float* kb = kp.p[s];
    _Float16* v8s = v8 + (long)s * ((long)NTOK * 64) + tok0 * 64;
    float* atts = att + (long)s * (B_ * 1024) + (long)b * 1024;

    // ---- phase 1: wave-local load of this wave's 16 k-input rows ----
    #pragma unroll
    for (int r = 0; r < 8; ++r) {
        int u = r * 64 + lane;
        int tok = tw0 + (u >> 5), c4 = u & 31;
        float4 v = *(const float4*)(kb + (tok0 + tok) * (long)ldk + c4 * 4);
        *(float4*)(sx + tok * 128 + c4 * 4) = v;
    }
    __builtin_amdgcn_wave_barrier();

    // ---- phase 2: folded K/V projection (pair-mean folded into weights) ----
    {
        const int j = lane;
        float ka[16], va[16];
        #pragma unroll
        for (int t = 0; t < 16; ++t) { ka[t] = 0.f; va[t] = 0.f; }
        for (int i = 0; i < 128; i += 4) {
            float wk[4], wv[4];
            #pragma unroll
            for (int u = 0; u < 4; ++u) {
                float2 a = *(const float2*)(Wk + (long)(i + u) * 128 + 2 * j);
                float2 c = *(const float2*)(Wv + (long)(i + u) * 128 + 2 * j);
                wk[u] = 0.5f * (a.x + a.y);
                wv[u] = 0.5f * (c.x + c.y);
            }
            #pragma unroll
            for (int t = 0; t < 16; ++t) {
                float4 xv = *(const float4*)(sx + (tw0 + t) * 128 + i);
                ka[t] += xv.x * wk[0] + xv.y * wk[1] + xv.z * wk[2] + xv.w * wk[3];
                va[t] += xv.x * wv[0] + xv.y * wv[1] + xv.z * wv[2] + xv.w * wv[3];
            }
        }
        #pragma unroll
        for (int t = 0; t < 16; ++t) {
            int tok = tw0 + t;
            sk8[tok * 64 + j] = ka[t];
            v8s[(long)tok * 64 + j] = (_Float16)va[t];
        }
    }
    __builtin_amdgcn_wave_barrier();

    // ---- phase 3: reload q rows if q-input differs ----
    if (qb != kb || ldq != ldk) {
        #pragma unroll
        for (int r = 0; r < 8; ++r) {
            int u = r * 64 + lane;
            int tok = tw0 + (u >> 5), c4 = u & 31;
            float4 v = *(const float4*)(qb + (tok0 + tok) * (long)ldq + c4 * 4);
            *(float4*)(sx + tok * 128 + c4 * 4) = v;
        }
        __builtin_amdgcn_wave_barrier();
    }

    // ---- phase 4: LN1, wave-local (4 lanes per token, shfl_xor reduce) ----
    {
        const int t = lane >> 2, part = lane & 3;
        float* xr = sx + (tw0 + t) * 128 + part * 32;
        float sum = 0.f;
        #pragma unroll
        for (int i = 0; i < 32; i += 4) {
            float4 v = *(const float4*)(xr + i);
            sum += v.x + v.y + v.z + v.w;
        }
        sum += __shfl_xor(sum, 1); sum += __shfl_xor(sum, 2);
        const float mu = sum * (1.f / 128.f);
        float ss = 0.f;
        #pragma unroll
        for (int i = 0; i < 32; i += 4) {
            float4 v = *(const float4*)(xr + i);
            float d0 = v.x - mu, d1 = v.y - mu, d2 = v.z - mu, d3 = v.w - mu;
            ss += d0 * d0 + d1 * d1 + d2 * d2 + d3 * d3;
        }
        ss += __shfl_xor(ss, 1); ss += __shfl_xor(ss, 2);
        const float rs = rsqrtf(ss * (1.f / 128.f) + EPS_);
        #pragma unroll
        for (int i = 0; i < 32; i += 4) {
            float4 v  = *(const float4*)(xr + i);
            float4 g  = *(const float4*)(lng + part * 32 + i);
            float4 bb = *(const float4*)(lnb + part * 32 + i);
            v.x = (v.x - mu) * rs * g.x + bb.x;
            v.y = (v.y - mu) * rs * g.y + bb.y;
            v.z = (v.z - mu) * rs * g.z + bb.z;
            v.w = (v.w - mu) * rs * g.w + bb.w;
            *(float4*)(xr + i) = v;
        }
    }
    __builtin_amdgcn_wave_barrier();

    // ---- phase 5: Q proj + score partials (wave-local rows) ----
    {
        const int j = lane;
        float qa0[16], qa1[16];
        #pragma unroll
        for (int t = 0; t < 16; ++t) { qa0[t] = 0.f; qa1[t] = 0.f; }
        for (int i = 0; i < 128; i += 4) {
            float w0[4], w1[4];
            #pragma unroll
            for (int u = 0; u < 4; ++u) {
                w0[u] = Wq[(long)(i + u) * 128 + j];
                w1[u] = Wq[(long)(i + u) * 128 + j + 64];
            }
            #pragma unroll
            for (int t = 0; t < 16; ++t) {
                float4 xv = *(const float4*)(sx + (tw0 + t) * 128 + i);
                qa0[t] += xv.x * w0[0] + xv.y * w0[1] + xv.z * w0[2] + xv.w * w0[3];
                qa1[t] += xv.x * w1[0] + xv.y * w1[1] + xv.z * w1[2] + xv.w * w1[3];
            }
        }
        #pragma unroll
        for (int fi = 0; fi < 2; ++fi) {
            int f = j + fi * 64;
            int h = f >> 4;
            float p[8];
            #pragma unroll
            for (int e = 0; e < 8; ++e) p[e] = 0.f;
            #pragma unroll
            for (int t = 0; t < 16; ++t) {
                int tok = tw0 + t;
                float4 k0 = *(const float4*)(sk8 + tok * 64 + h * 8);
                float4 k1 = *(const float4*)(sk8 + tok * 64 + h * 8 + 4);
                float q = fi ? qa1[t] : qa0[t];
                p[0] += q * k0.x; p[1] += q * k0.y; p[2] += q * k0.z; p[3] += q * k0.w;
                p[4] += q * k1.x; p[5] += q * k1.y; p[6] += q * k1.z; p[7] += q * k1.w;
            }
            #pragma unroll
            for (int e = 0; e < 8; ++e) spart[(w * 128 + f) * 8 + e] = p[e];
        }
    }
    __syncthreads();    // the ONLY block-wide barrier: cross-wave reduce
    for (int idx = tid; idx < 1024; idx += 256) {
        float v = spart[idx] + spart[1024 + idx] + spart[2048 + idx] + spart[3072 + idx];
        atomicAdd(atts + idx, v);
    }
}

// ---------------------------------------------------------------------------
// Kernel C (MFMA, fp16, swapped operands, 2 token-tiles per block):
// block = 128 tokens; wave owns rows {w*16+l16, w*16+l16+64}.  Every weight
// fragment is loaded ONCE and feeds TWO independent MFMAs (tile A, tile B):
// halves the latency-bound L2 weight-load count per MFMA and doubles ILP.
// Residual x seeds the Wfc MFMA C-operand; y+b2 seeds the FFN2 accumulator,
// so the final store is the accumulator directly (keeps VGPR bounded).
// Single __syncthreads (s_att broadcast).  LDS = 4KB + 34.8KB.
// ---------------------------------------------------------------------------
__global__ __launch_bounds__(256) void enc_post_mfma(
    P4 xp, int ldx, P4 op, int ldo,
    const _Float16* __restrict__ v8, const float* __restrict__ att,
    const _Float16* __restrict__ Wfcp,
    const float* __restrict__ lng, const float* __restrict__ lnb,
    const _Float16* __restrict__ W1p, const float* __restrict__ bv1,
    const _Float16* __restrict__ W2p, const float* __restrict__ bv2)
{
    __shared__ float s_att[1024];
    __shared__ _Float16 s_x[128 * 136];  // [token][128 + 8 pad] halves

    const int tid  = threadIdx.x;
    const int w    = tid >> 6;          // wave 0..3
    const int lane = tid & 63;
    const int quad = lane >> 4, l16 = lane & 15;
    const int bx   = blockIdx.x;
    const int s    = bx >> 10;          // 1024 blocks per stream
    const int blk  = bx & 1023;
    const long tok0 = (long)blk * 128;
    const int b = blk >> 4;             // 16 blocks per sequence

    const float* xb = xp.p[s];
    float* ob = (float*)op.p[s];
    const _Float16* v8s = v8 + (long)s * ((long)NTOK * 64) + tok0 * 64;
    const float* atts = att + (long)s * (B_ * 1024) + (long)b * 1024;

    const int trA = w * 16 + l16;       // tile-A token row (0..63)
    const int trB = trA + 64;           // tile-B token row (64..127)

    if (tid < 128) {                    // softmax rows h*16+d
        float sc[8];
        #pragma unroll
        for (int e = 0; e < 8; ++e) sc[e] = atts[tid * 8 + e] * INV_TEMP;
        float m = sc[0];
        #pragma unroll
        for (int e = 1; e < 8; ++e) m = fmaxf(m, sc[e]);
        float sum = 0.f;
        #pragma unroll
        for (int e = 0; e < 8; ++e) { sc[e] = expf(sc[e] - m); sum += sc[e]; }
        float inv = 1.f / sum;
        #pragma unroll
        for (int e = 0; e < 8; ++e) s_att[tid * 8 + e] = sc[e] * inv;
    }
    __syncthreads();                    // the ONLY block-wide barrier

    // ---- v rows for both tiles (16 independent 16B loads -> high MLP) ----
    half8 hvA[8], hvB[8];
    {
        const _Float16* vra = v8s + (long)trA * 64;
        const _Float16* vrb = v8s + (long)trB * 64;
        #pragma unroll
        for (int j = 0; j < 8; ++j) {
            hvA[j] = *(const half8*)(vra + j * 8);
            hvB[j] = *(const half8*)(vrb + j * 8);
        }
    }

    // ---- attn apply -> fragments for both tiles; s_att reads shared ----
    half8 afragA[4], afragB[4];
    {
        float aoA[4][8], aoB[4][8];
        #pragma unroll
        for (int j = 0; j < 8; ++j) {
            #pragma unroll
            for (int kt = 0; kt < 4; ++kt) {
                const float* ar = s_att + (j * 16 + kt * 4 + quad) * 8;
                float4 a0 = *(const float4*)ar;
                float4 a1 = *(const float4*)(ar + 4);
                float vA = (float)hvA[j][0] * a0.x + (float)hvA[j][1] * a0.y
                         + (float)hvA[j][2] * a0.z + (float)hvA[j][3] * a0.w
                         + (float)hvA[j][4] * a1.x + (float)hvA[j][5] * a1.y
                         + (float)hvA[j][6] * a1.z + (float)hvA[j][7] * a1.w;
                float vB = (float)hvB[j][0] * a0.x + (float)hvB[j][1] * a0.y
                         + (float)hvB[j][2] * a0.z + (float)hvB[j][3] * a0.w
                         + (float)hvB[j][4] * a1.x + (float)hvB[j][5] * a1.y
                         + (float)hvB[j][6] * a1.z + (float)hvB[j][7] * a1.w;
                aoA[kt][j] = vA;
                aoB[kt][j] = vB;
            }
        }
        #pragma unroll
        for (int kt = 0; kt < 4; ++kt)
            #pragma unroll
            for (int j = 0; j < 8; ++j) {
                afragA[kt][j] = (_Float16)aoA[kt][j];
                afragB[kt][j] = (_Float16)aoB[kt][j];
            }
    }

    // ---- Wfc swapped, residual-seeded: yacc = x + attn_out @ Wfc ----
    f32x4 yaccA[8], yaccB[8];
    {
        const float* xrowA = xb + (tok0 + trA) * (long)ldx;
        const float* xrowB = xb + (tok0 + trB) * (long)ldx;
        #pragma unroll
        for (int nt = 0; nt < 8; ++nt) {
            yaccA[nt] = *(const f32x4*)(xrowA + nt * 16 + quad * 4);
            yaccB[nt] = *(const f32x4*)(xrowB + nt * 16 + quad * 4);
        }
    }
    #pragma unroll
    for (int nt = 0; nt < 8; ++nt) {
        #pragma unroll
        for (int kt = 0; kt < 4; ++kt) {
            half8 wf = *(const half8*)(Wfcp + ((nt * 4 + kt) * 64 + lane) * 8);
            yaccA[nt] = __builtin_amdgcn_mfma_f32_16x16x32_f16(wf, afragA[kt], yaccA[nt], 0, 0, 0);
            yaccB[nt] = __builtin_amdgcn_mfma_f32_16x16x32_f16(wf, afragB[kt], yaccB[nt], 0, 0, 0);
        }
    }

    // ---- LN2 per tile: in-lane 32-sum + quad butterfly (xor 16, 32) ----
    float muA, rsA, muB, rsB;
    {
        float smA = 0.f, smB = 0.f;
        #pragma unroll
        for (int nt = 0; nt < 8; ++nt)
            #pragma unroll
            for (int r = 0; r < 4; ++r) { smA += yaccA[nt][r]; smB += yaccB[nt][r]; }
        smA += __shfl_xor(smA, 16); smA += __shfl_xor(smA, 32);
        smB += __shfl_xor(smB, 16); smB += __shfl_xor(smB, 32);
        muA = smA * (1.f / 128.f); muB = smB * (1.f / 128.f);
        float ssA = 0.f, ssB = 0.f;
        #pragma unroll
        for (int nt = 0; nt < 8; ++nt)
            #pragma unroll
            for (int r = 0; r < 4; ++r) {
                float dA = yaccA[nt][r] - muA; ssA += dA * dA;
                float dB = yaccB[nt][r] - muB; ssB += dB * dB;
            }
        ssA += __shfl_xor(ssA, 16); ssA += __shfl_xor(ssA, 32);
        ssB += __shfl_xor(ssB, 16); ssB += __shfl_xor(ssB, 32);
        rsA = rsqrtf(ssA * (1.f / 128.f) + EPS_);
        rsB = rsqrtf(ssB * (1.f / 128.f) + EPS_);
    }

    // ---- xn -> LDS [token][feat] (b64 writes, wave-local rows), then fold
    //      b2 into yacc so it becomes the FFN2 accumulator/final value ----
    #pragma unroll
    for (int nt = 0; nt < 8; ++nt) {
        f32x4 g  = *(const f32x4*)(lng + nt * 16 + quad * 4);
        f32x4 bb = *(const f32x4*)(lnb + nt * 16 + quad * 4);
        f32x4 b2v = *(const f32x4*)(bv2 + nt * 16 + quad * 4);
        half4 ha, hb;
        #pragma unroll
        for (int r = 0; r < 4; ++r) {
            ha[r] = (_Float16)((yaccA[nt][r] - muA) * rsA * g[r] + bb[r]);
            hb[r] = (_Float16)((yaccB[nt][r] - muB) * rsB * g[r] + bb[r]);
        }
        *(half4*)(s_x + trA * 136 + nt * 16 + quad * 4) = ha;
        *(half4*)(s_x + trB * 136 + nt * 16 + quad * 4) = hb;
        yaccA[nt] += b2v;
        yaccB[nt] += b2v;
    }
    // same-wave DS ordering: rows trA/trB are wave-local.
    half8 xfragA[4], xfragB[4];
    #pragma unroll
    for (int kt = 0; kt < 4; ++kt) {
        xfragA[kt] = *(const half8*)(s_x + trA * 136 + kt * 32 + quad * 8);
        xfragB[kt] = *(const half8*)(s_x + trB * 136 + kt * 32 + quad * 8);
    }

    // ---- FFN: 4 chunks of 128 hidden; weight frags shared by both tiles ----
    for (int ch = 0; ch < 4; ++ch) {
        #pragma unroll
        for (int tl = 0; tl < 8; ++tl) {
            f32x4 bv = *(const f32x4*)(bv1 + ch * 128 + tl * 16 + quad * 4);
            f32x4 c1A = bv, c1B = bv;          // bias-seeded accumulators
            #pragma unroll
            for (int kt = 0; kt < 4; ++kt) {
                half8 wf = *(const half8*)(W1p + (((ch * 8 + tl) * 4 + kt) * 64 + lane) * 8);
                c1A = __builtin_amdgcn_mfma_f32_16x16x32_f16(wf, xfragA[kt], c1A, 0, 0, 0);
                c1B = __builtin_amdgcn_mfma_f32_16x16x32_f16(wf, xfragB[kt], c1B, 0, 0, 0);
            }
            half4 ha, hb;
            #pragma unroll
            for (int r = 0; r < 4; ++r) {
                float hxA = c1A[r];
                float eA = __expf(fminf(hxA, 30.f));
                float tA = 1.f + eA, t2A = tA * tA;
                ha[r] = (_Float16)(hxA * (t2A - 1.f) * __builtin_amdgcn_rcpf(t2A + 1.f));
                float hxB = c1B[r];
                float eB = __expf(fminf(hxB, 30.f));
                float tB = 1.f + eB, t2B = tB * tB;
                hb[r] = (_Float16)(hxB * (t2B - 1.f) * __builtin_amdgcn_rcpf(t2B + 1.f));
            }
            *(half4*)(s_x + trA * 136 + tl * 16 + quad * 4) = ha;
            *(half4*)(s_x + trB * 136 + tl * 16 + quad * 4) = hb;
        }
        half8 hfragA[4], hfragB[4];
        #pragma unroll
        for (int ks = 0; ks < 4; ++ks) {
            hfragA[ks] = *(const half8*)(s_x + trA * 136 + ks * 32 + quad * 8);
            hfragB[ks] = *(const half8*)(s_x + trB * 136 + ks * 32 + quad * 8);
        }
        #pragma unroll
        for (int nt = 0; nt < 8; ++nt) {
            #pragma unroll
            for (int ks = 0; ks < 4; ++ks) {
                half8 wf = *(const half8*)(W2p + ((nt * 16 + ch * 4 + ks) * 64 + lane) * 8);
                yaccA[nt] = __builtin_amdgcn_mfma_f32_16x16x32_f16(wf, hfragA[ks], yaccA[nt], 0, 0, 0);
                yaccB[nt] = __builtin_amdgcn_mfma_f32_16x16x32_f16(wf, hfragB[ks], yaccB[nt], 0, 0, 0);
            }
        }
    }

    // ---- out = yacc (already z + b2 + y)  (float4 stores) ----
    {
        float* orowA = ob + (tok0 + trA) * (long)ldo;
        float* orowB = ob + (tok0 + trB) * (long)ldo;
        #pragma unroll
        for (int nt = 0; nt < 8; ++nt) {
            *(f32x4*)(orowA + nt * 16 + quad * 4) = yaccA[nt];
            *(f32x4*)(orowB + nt * 16 + quad * 4) = yaccB[nt];
        }
    }
}

// ---------------------------------------------------------------------------
// enc0 = concat(e1, e2) @ WL2 + bL2
// ---------------------------------------------------------------------------
__global__ __launch_bounds__(256) void enc_combine(
    const float* __restrict__ e1, const float* __restrict__ e2,
    float* __restrict__ outp,
    const float* __restrict__ W, const float* __restrict__ bias)
{
    __shared__ float sc[32 * 256];
    const int tid = threadIdx.x;
    const long tok0 = (long)blockIdx.x * 32;
    #pragma unroll
    for (int r = 0; r < 4; ++r) {
        int u = tid + r * 256;
        int tok = u >> 5, c4 = u & 31;
        *(float4*)(sc + tok * 256 + c4 * 4)       = *(const float4*)(e1 + (tok0 + tok) * 128 + c4 * 4);
        *(float4*)(sc + tok * 256 + 128 + c4 * 4) = *(const float4*)(e2 + (tok0 + tok) * 128 + c4 * 4);
    }
    __syncthreads();
    const int j = tid & 63, tg = tid >> 6;
    float a0[8], a1[8];
    #pragma unroll
    for (int t = 0; t < 8; ++t) { a0[t] = 0.f; a1[t] = 0.f; }
    for (int i = 0; i < 256; i += 4) {
        float w0[4], w1[4];
        #pragma unroll
        for (int u = 0; u < 4; ++u) {
            w0[u] = W[(long)(i + u) * 128 + j];
            w1[u] = W[(long)(i + u) * 128 + j + 64];
        }
        #pragma unroll
        for (int t = 0; t < 8; ++t) {
            float4 xv = *(const float4*)(sc + (tg * 8 + t) * 256 + i);
            a0[t] += xv.x * w0[0] + xv.y * w0[1] + xv.z * w0[2] + xv.w * w0[3];
            a1[t] += xv.x * w1[0] + xv.y * w1[1] + xv.z * w1[2] + xv.w * w1[3];
        }
    }
    float b0 = bias[j], b1 = bias[j + 64];
    #pragma unroll
    for (int t = 0; t < 8; ++t) {
        int tok = tg * 8 + t;
        outp[(tok0 + tok) * 128 + j]      = a0[t] + b0;
        outp[(tok0 + tok) * 128 + j + 64] = a1[t] + b1;
    }
}

// ---------------------------------------------------------------------------
extern "C" void kernel_launch(void* const* d_in, const int* in_sizes, int n_in,
                              void* d_out, int out_size, void* d_ws, size_t ws_size,
                              hipStream_t stream)
{
    const float* src  = (const float*)d_in[0];
    const float* ln1g = (const float*)d_in[2];
    const float* ln1b = (const float*)d_in[3];
    const float* Wq   = (const float*)d_in[4];
    const float* Wk   = (const float*)d_in[5];
    const float* Wv   = (const float*)d_in[6];
    const float* Wfc  = (const float*)d_in[7];
    const float* ln2g = (const float*)d_in[8];
    const float* ln2b = (const float*)d_in[9];
    const float* W1   = (const float*)d_in[10];
    const float* b1   = (const float*)d_in[11];
    const float* W2   = (const float*)d_in[12];
    const float* b2   = (const float*)d_in[13];
    const float* WL2  = (const float*)d_in[14];
    const float* bL2  = (const float*)d_in[15];
    float* out = (float*)d_out;

    const long TOKS = (long)NTOK * 128;
    float* ws  = (float*)d_ws;
    float* XE1 = ws;
    float* XE2 = ws + TOKS;
    _Float16* V8 = (_Float16*)(ws + 2 * TOKS);          // 4*NTOK*64 fp16
    float* ATT = (float*)(V8 + 4L * NTOK * 64);         // 4*B*1024 f32
    _Float16* WPfc = (_Float16*)(ATT + 4 * B_ * 1024);  // 4*16384
    _Float16* WP1  = WPfc + 4L * 16384;                 // 4*65536
    _Float16* WP2  = WP1 + 4L * 65536;                  // 4*65536
    if (ws_size < 205000000ULL) return;

    float* m1b  = out + TOKS;
    float* m2b  = out + 2 * TOKS;
    float* encb = out;
    const float* bufs[4] = { m1b, m2b, XE1, XE2 };

    // ---- pack weights to fp16 fragment order (d_ws re-poisoned per call) ----
    pack_b<<<dim3(64, 4),  dim3(256), 0, stream>>>(Wfc, WPfc, 128, 128);
    pack_b<<<dim3(256, 4), dim3(256), 0, stream>>>(W1,  WP1,  128, 512);
    pack_b<<<dim3(256, 4), dim3(256), 0, stream>>>(W2,  WP2,  512, 128);

    // ---- stacked phase: streams {m1, m2, e1, e2} ----
    for (int l = 0; l < 4; ++l) {
        hipMemsetAsync(ATT, 0, 4 * B_ * 1024 * sizeof(float), stream);
        P4 qp, kp, op;
        int ldq, ldk;
        if (l == 0) {
            qp = P4{{ src, src + 128, src + 128, src }};  ldq = 256;
            kp = P4{{ src, src + 128, src, src + 128 }};  ldk = 256;
        } else {
            qp = P4{{ bufs[0], bufs[1], bufs[2], bufs[3] }}; ldq = 128;
            kp = qp; ldk = 128;
        }
        op = P4{{ bufs[0], bufs[1], bufs[2], bufs[3] }};
        const long wo = (long)l * 128 * 128;
        enc_qkv_attn<<<dim3(4 * 2048), dim3(256), 0, stream>>>(
            qp, ldq, kp, ldk, V8, ATT,
            Wq + wo, Wk + wo, Wv + wo, ln1g + l * 128, ln1b + l * 128);
        enc_post_mfma<<<dim3(4 * 1024), dim3(256), 0, stream>>>(
            qp, ldq, op, 128, V8, ATT,
            WPfc + (long)l * 16384, ln2g + l * 128, ln2b + l * 128,
            WP1 + (long)l * 65536, b1 + l * 512,
            WP2 + (long)l * 65536, b2 + l * 128);
    }

    // ---- enc = concat(e1,e2) @ WL2 + bL2 ----
    enc_combine<<<dim3(4096), dim3(256), 0, stream>>>(XE1, XE2, encb, WL2, bL2);

    // ---- enc phase ----
    for (int l = 0; l < 4; ++l) {
        hipMemsetAsync(ATT, 0, B_ * 1024 * sizeof(float), stream);
        P4 p = P4{{ encb, encb, encb, encb }};
        const long wo = (long)l * 128 * 128;
        enc_qkv_attn<<<dim3(2048), dim3(256), 0, stream>>>(
            p, 128, p, 128, V8, ATT,
            Wq + wo, Wk + wo, Wv + wo, ln1g + l * 128, ln1b + l * 128);
        enc_post_mfma<<<dim3(1024), dim3(256), 0, stream>>>(
            p, 128, p, 128, V8, ATT,
            WPfc + (long)l * 16384, ln2g + l * 128, ln2b + l * 128,
            WP1 + (long)l * 65536, b1 + l * 512,
            WP2 + (long)l * 65536, b2 + l * 128);
    }
}

// Round 7
// 5892.862 us; speedup vs baseline: 1.7364x; 1.2960x over previous
//
#include <hip/hip_runtime.h>
#include <math.h>

// Problem constants (from reference)
#define H_    8
#define DK_   16
#define DM_   128
#define DI_   512
#define B_    64
#define S_    2048
#define NTOK  131072          // B_*S_
#define EPS_  1e-6f
#define INV_TEMP 0.5f         // TEMP = 0.5*sqrt(16) = 2.0

typedef __attribute__((ext_vector_type(8))) _Float16 half8;
typedef __attribute__((ext_vector_type(4))) _Float16 half4;
typedef __attribute__((ext_vector_type(4))) float f32x4;

struct P4 { const float* p[4]; };

// ---------------------------------------------------------------------------
// Pack a K x N f32 weight (row-major) into fp16 fragment order for
// mfma_f32_16x16x32_f16: flat[((nt*(K/32)+kt)*64 + lane)*8 + j] =
//   W[kt*32 + (lane>>4)*8 + j][nt*16 + (lane&15)].  blockIdx.y = layer.
// This layout is BOTH the B-frag of W and the A-frag of W^T (identical lane
// mapping), so swapped-operand MFMA (transposed output) needs no new pack.
// ---------------------------------------------------------------------------
__global__ __launch_bounds__(256) void pack_b(
    const float* __restrict__ W, _Float16* __restrict__ out, int K, int N)
{
    long base = (long)blockIdx.y * K * N;
    int idx = blockIdx.x * 256 + threadIdx.x;
    if (idx >= K * N) return;
    int j = idx & 7;
    int lane = (idx >> 3) & 63;
    int t = idx >> 9;                 // tile = nt*(K/32)+kt
    int KT = K >> 5;
    int nt = t / KT, kt = t - nt * KT;
    int k = kt * 32 + (lane >> 4) * 8 + j;
    int n = nt * 16 + (lane & 15);
    out[base + idx] = (_Float16)W[base + (long)k * N + n];
}

// ---------------------------------------------------------------------------
// Fold pair-mean (adjacent output columns) of a 128x128 weight into a 128x64
// fp16 fragment-packed weight.  folded[k][n] = 0.5*(W[k][2n] + W[k][2n+1]).
// Output fragment order identical to pack_b with K=128, N=64 (KT=4, NT=4).
// ---------------------------------------------------------------------------
__global__ __launch_bounds__(256) void pack_fold(
    const float* __restrict__ W, _Float16* __restrict__ out)
{
    long wbase = (long)blockIdx.y * 128 * 128;
    long obase = (long)blockIdx.y * 128 * 64;
    int idx = blockIdx.x * 256 + threadIdx.x;   // 32 blocks * 256 = 8192
    int j = idx & 7;
    int lane = (idx >> 3) & 63;
    int t = idx >> 9;                 // tile = nt*4 + kt
    int nt = t >> 2, kt = t & 3;
    int k = kt * 32 + (lane >> 4) * 8 + j;
    int n = nt * 16 + (lane & 15);
    float v = 0.5f * (W[wbase + (long)k * 128 + 2 * n]
                    + W[wbase + (long)k * 128 + 2 * n + 1]);
    out[obase + idx] = (_Float16)v;
}

// ---------------------------------------------------------------------------
// Kernel A v2 (MFMA): per 64-token tile, 4 waves, wave owns 16 tokens
// (token = w*16 + (lane&15)).  K/V/Q projections via swapped-operand MFMA
// (64 MFMA/wave replaces ~8.5K scalar FMAs).  LN1 stats from global with
// in-register butterfly (no conflicted LDS passes).  k8/q stored fp16 in
// small padded LDS; score partials via bank-staggered LDS atomics (4KB).
// LDS total ~31KB (was 64KB).  Two barriers.
// ---------------------------------------------------------------------------
__global__ __launch_bounds__(256) void enc_qkv_attn(
    P4 qp, int ldq, P4 kp, int ldk,
    _Float16* __restrict__ v8, float* __restrict__ att,
    const _Float16* __restrict__ Wqp, const _Float16* __restrict__ Wkp,
    const _Float16* __restrict__ Wvp,
    const float* __restrict__ lng, const float* __restrict__ lnb)
{
    __shared__ _Float16 s_xn[64 * 136];   // XN fp16, then q fp16 (17.4KB)
    __shared__ _Float16 s_k[64 * 72];     // k8 fp16 [tok][64+8 pad] (9.2KB)
    __shared__ float s_p[1024];           // score accumulator (4KB)

    const int tid  = threadIdx.x;
    const int w    = tid >> 6;            // wave 0..3
    const int lane = tid & 63;
    const int quad = lane >> 4, l16 = lane & 15;
    const int bx   = blockIdx.x;
    const int s    = bx >> 11;
    const int blk  = bx & 2047;
    const long tok0 = (long)blk * 64;
    const int b = blk >> 5;
    const int trow = w * 16 + l16;        // this lane's token row (0..63)
    const long gtok = tok0 + trow;

    const float* qb = qp.p[s];
    const float* kb = kp.p[s];
    _Float16* v8s = v8 + (long)s * ((long)NTOK * 64) + tok0 * 64;
    float* atts = att + (long)s * (B_ * 1024) + (long)b * 1024;

    for (int i = tid; i < 1024; i += 256) s_p[i] = 0.f;

    // ---- K/V input fragments straight from global (raw k-input) ----
    half8 xk[4];
    #pragma unroll
    for (int kt = 0; kt < 4; ++kt) {
        f32x4 a = *(const f32x4*)(kb + gtok * (long)ldk + kt * 32 + quad * 8);
        f32x4 c = *(const f32x4*)(kb + gtok * (long)ldk + kt * 32 + quad * 8 + 4);
        #pragma unroll
        for (int r = 0; r < 4; ++r) {
            xk[kt][r]     = (_Float16)a[r];
            xk[kt][r + 4] = (_Float16)c[r];
        }
    }

    // ---- K proj (folded) MFMA -> k8^T -> s_k fp16 [tok][feat] ----
    #pragma unroll
    for (int nt = 0; nt < 4; ++nt) {
        f32x4 c = {0.f, 0.f, 0.f, 0.f};
        #pragma unroll
        for (int kt = 0; kt < 4; ++kt) {
            half8 wf = *(const half8*)(Wkp + ((nt * 4 + kt) * 64 + lane) * 8);
            c = __builtin_amdgcn_mfma_f32_16x16x32_f16(wf, xk[kt], c, 0, 0, 0);
        }
        half4 hv;
        #pragma unroll
        for (int r = 0; r < 4; ++r) hv[r] = (_Float16)c[r];
        *(half4*)(s_k + trow * 72 + nt * 16 + quad * 4) = hv;
    }

    // ---- V proj (folded) MFMA -> global v8 fp16 [tok][feat] ----
    #pragma unroll
    for (int nt = 0; nt < 4; ++nt) {
        f32x4 c = {0.f, 0.f, 0.f, 0.f};
        #pragma unroll
        for (int kt = 0; kt < 4; ++kt) {
            half8 wf = *(const half8*)(Wvp + ((nt * 4 + kt) * 64 + lane) * 8);
            c = __builtin_amdgcn_mfma_f32_16x16x32_f16(wf, xk[kt], c, 0, 0, 0);
        }
        half4 hv;
        #pragma unroll
        for (int r = 0; r < 4; ++r) hv[r] = (_Float16)c[r];
        *(half4*)(v8s + (long)trow * 64 + nt * 16 + quad * 4) = hv;
    }

    // ---- LN1 from global q-input; stats via in-register + quad butterfly ----
    f32x4 xq[8];       // token trow, feats quad*32 .. quad*32+31
    #pragma unroll
    for (int k = 0; k < 8; ++k)
        xq[k] = *(const f32x4*)(qb + gtok * (long)ldq + quad * 32 + k * 4);
    float mu, rs;
    {
        float sm = 0.f;
        #pragma unroll
        for (int k = 0; k < 8; ++k)
            #pragma unroll
            for (int r = 0; r < 4; ++r) sm += xq[k][r];
        sm += __shfl_xor(sm, 16); sm += __shfl_xor(sm, 32);
        mu = sm * (1.f / 128.f);
        float ss = 0.f;
        #pragma unroll
        for (int k = 0; k < 8; ++k)
            #pragma unroll
            for (int r = 0; r < 4; ++r) { float d = xq[k][r] - mu; ss += d * d; }
        ss += __shfl_xor(ss, 16); ss += __shfl_xor(ss, 32);
        rs = rsqrtf(ss * (1.f / 128.f) + EPS_);
    }
    // normalized XN -> s_xn fp16 [tok][feat]
    #pragma unroll
    for (int k = 0; k < 8; ++k) {
        f32x4 g  = *(const f32x4*)(lng + quad * 32 + k * 4);
        f32x4 bb = *(const f32x4*)(lnb + quad * 32 + k * 4);
        half4 hv;
        #pragma unroll
        for (int r = 0; r < 4; ++r)
            hv[r] = (_Float16)((xq[k][r] - mu) * rs * g[r] + bb[r]);
        *(half4*)(s_xn + trow * 136 + quad * 32 + k * 4) = hv;
    }

    // ---- Q fragments (wave-local rows; same-wave DS ordering) + MFMA ----
    half8 xn[4];
    #pragma unroll
    for (int kt = 0; kt < 4; ++kt)
        xn[kt] = *(const half8*)(s_xn + trow * 136 + kt * 32 + quad * 8);
    f32x4 qa[8];
    #pragma unroll
    for (int nt = 0; nt < 8; ++nt) {
        f32x4 c = {0.f, 0.f, 0.f, 0.f};
        #pragma unroll
        for (int kt = 0; kt < 4; ++kt) {
            half8 wf = *(const half8*)(Wqp + ((nt * 4 + kt) * 64 + lane) * 8);
            c = __builtin_amdgcn_mfma_f32_16x16x32_f16(wf, xn[kt], c, 0, 0, 0);
        }
        qa[nt] = c;
    }
    // overwrite s_xn with q fp16 (reads above precede writes in program order)
    #pragma unroll
    for (int nt = 0; nt < 8; ++nt) {
        half4 hv;
        #pragma unroll
        for (int r = 0; r < 4; ++r) hv[r] = (_Float16)qa[nt][r];
        *(half4*)(s_xn + trow * 136 + nt * 16 + quad * 4) = hv;
    }

    __syncthreads();   // barrier 1: q, k8, s_p-zero visible block-wide

    // ---- score partials over this wave's 16 tokens (lane j: feats j, j+64) ----
    {
        const int j = lane;
        const int h0 = j >> 4, h1 = (j + 64) >> 4;
        float p0[8], p1[8];
        #pragma unroll
        for (int e = 0; e < 8; ++e) { p0[e] = 0.f; p1[e] = 0.f; }
        #pragma unroll
        for (int t = 0; t < 16; ++t) {
            int tok = w * 16 + t;
            float q0 = (float)s_xn[tok * 136 + j];
            float q1 = (float)s_xn[tok * 136 + j + 64];
            half8 k0 = *(const half8*)(s_k + tok * 72 + h0 * 8);
            half8 k1 = *(const half8*)(s_k + tok * 72 + h1 * 8);
            #pragma unroll
            for (int e = 0; e < 8; ++e) {
                p0[e] += q0 * (float)k0[e];
                p1[e] += q1 * (float)k1[e];
            }
        }
        // bank-staggered LDS atomics (e-order rotated by j>>2 -> 2-way max)
        #pragma unroll
        for (int ee = 0; ee < 8; ++ee) {
            int e = (ee + (j >> 2)) & 7;
            atomicAdd(&s_p[j * 8 + e], p0[e]);
            atomicAdd(&s_p[(j + 64) * 8 + e], p1[e]);
        }
    }
    __syncthreads();   // barrier 2: all partials in s_p
    for (int i = tid; i < 1024; i += 256)
        atomicAdd(atts + i, s_p[i]);
}

// ---------------------------------------------------------------------------
// Kernel C (MFMA, fp16, swapped operands, 2 token-tiles per block):
// unchanged from round 5 (verified: 8764 -> 7637 total).
// ---------------------------------------------------------------------------
__global__ __launch_bounds__(256) void enc_post_mfma(
    P4 xp, int ldx, P4 op, int ldo,
    const _Float16* __restrict__ v8, const float* __restrict__ att,
    const _Float16* __restrict__ Wfcp,
    const float* __restrict__ lng, const float* __restrict__ lnb,
    const _Float16* __restrict__ W1p, const float* __restrict__ bv1,
    const _Float16* __restrict__ W2p, const float* __restrict__ bv2)
{
    __shared__ float s_att[1024];
    __shared__ _Float16 s_x[128 * 136];  // [token][128 + 8 pad] halves

    const int tid  = threadIdx.x;
    const int w    = tid >> 6;          // wave 0..3
    const int lane = tid & 63;
    const int quad = lane >> 4, l16 = lane & 15;
    const int bx   = blockIdx.x;
    const int s    = bx >> 10;          // 1024 blocks per stream
    const int blk  = bx & 1023;
    const long tok0 = (long)blk * 128;
    const int b = blk >> 4;             // 16 blocks per sequence

    const float* xb = xp.p[s];
    float* ob = (float*)op.p[s];
    const _Float16* v8s = v8 + (long)s * ((long)NTOK * 64) + tok0 * 64;
    const float* atts = att + (long)s * (B_ * 1024) + (long)b * 1024;

    const int trA = w * 16 + l16;       // tile-A token row (0..63)
    const int trB = trA + 64;           // tile-B token row (64..127)

    if (tid < 128) {                    // softmax rows h*16+d
        float sc[8];
        #pragma unroll
        for (int e = 0; e < 8; ++e) sc[e] = atts[tid * 8 + e] * INV_TEMP;
        float m = sc[0];
        #pragma unroll
        for (int e = 1; e < 8; ++e) m = fmaxf(m, sc[e]);
        float sum = 0.f;
        #pragma unroll
        for (int e = 0; e < 8; ++e) { sc[e] = expf(sc[e] - m); sum += sc[e]; }
        float inv = 1.f / sum;
        #pragma unroll
        for (int e = 0; e < 8; ++e) s_att[tid * 8 + e] = sc[e] * inv;
    }
    __syncthreads();                    // the ONLY block-wide barrier

    // ---- v rows for both tiles (16 independent 16B loads -> high MLP) ----
    half8 hvA[8], hvB[8];
    {
        const _Float16* vra = v8s + (long)trA * 64;
        const _Float16* vrb = v8s + (long)trB * 64;
        #pragma unroll
        for (int j = 0; j < 8; ++j) {
            hvA[j] = *(const half8*)(vra + j * 8);
            hvB[j] = *(const half8*)(vrb + j * 8);
        }
    }

    // ---- attn apply -> fragments for both tiles; s_att reads shared ----
    half8 afragA[4], afragB[4];
    {
        float aoA[4][8], aoB[4][8];
        #pragma unroll
        for (int j = 0; j < 8; ++j) {
            #pragma unroll
            for (int kt = 0; kt < 4; ++kt) {
                const float* ar = s_att + (j * 16 + kt * 4 + quad) * 8;
                float4 a0 = *(const float4*)ar;
                float4 a1 = *(const float4*)(ar + 4);
                float vA = (float)hvA[j][0] * a0.x + (float)hvA[j][1] * a0.y
                         + (float)hvA[j][2] * a0.z + (float)hvA[j][3] * a0.w
                         + (float)hvA[j][4] * a1.x + (float)hvA[j][5] * a1.y
                         + (float)hvA[j][6] * a1.z + (float)hvA[j][7] * a1.w;
                float vB = (float)hvB[j][0] * a0.x + (float)hvB[j][1] * a0.y
                         + (float)hvB[j][2] * a0.z + (float)hvB[j][3] * a0.w
                         + (float)hvB[j][4] * a1.x + (float)hvB[j][5] * a1.y
                         + (float)hvB[j][6] * a1.z + (float)hvB[j][7] * a1.w;
                aoA[kt][j] = vA;
                aoB[kt][j] = vB;
            }
        }
        #pragma unroll
        for (int kt = 0; kt < 4; ++kt)
            #pragma unroll
            for (int j = 0; j < 8; ++j) {
                afragA[kt][j] = (_Float16)aoA[kt][j];
                afragB[kt][j] = (_Float16)aoB[kt][j];
            }
    }

    // ---- Wfc swapped, residual-seeded: yacc = x + attn_out @ Wfc ----
    f32x4 yaccA[8], yaccB[8];
    {
        const float* xrowA = xb + (tok0 + trA) * (long)ldx;
        const float* xrowB = xb + (tok0 + trB) * (long)ldx;
        #pragma unroll
        for (int nt = 0; nt < 8; ++nt) {
            yaccA[nt] = *(const f32x4*)(xrowA + nt * 16 + quad * 4);
            yaccB[nt] = *(const f32x4*)(xrowB + nt * 16 + quad * 4);
        }
    }
    #pragma unroll
    for (int nt = 0; nt < 8; ++nt) {
        #pragma unroll
        for (int kt = 0; kt < 4; ++kt) {
            half8 wf = *(const half8*)(Wfcp + ((nt * 4 + kt) * 64 + lane) * 8);
            yaccA[nt] = __builtin_amdgcn_mfma_f32_16x16x32_f16(wf, afragA[kt], yaccA[nt], 0, 0, 0);
            yaccB[nt] = __builtin_amdgcn_mfma_f32_16x16x32_f16(wf, afragB[kt], yaccB[nt], 0, 0, 0);
        }
    }

    // ---- LN2 per tile: in-lane 32-sum + quad butterfly (xor 16, 32) ----
    float muA, rsA, muB, rsB;
    {
        float smA = 0.f, smB = 0.f;
        #pragma unroll
        for (int nt = 0; nt < 8; ++nt)
            #pragma unroll
            for (int r = 0; r < 4; ++r) { smA += yaccA[nt][r]; smB += yaccB[nt][r]; }
        smA += __shfl_xor(smA, 16); smA += __shfl_xor(smA, 32);
        smB += __shfl_xor(smB, 16); smB += __shfl_xor(smB, 32);
        muA = smA * (1.f / 128.f); muB = smB * (1.f / 128.f);
        float ssA = 0.f, ssB = 0.f;
        #pragma unroll
        for (int nt = 0; nt < 8; ++nt)
            #pragma unroll
            for (int r = 0; r < 4; ++r) {
                float dA = yaccA[nt][r] - muA; ssA += dA * dA;
                float dB = yaccB[nt][r] - muB; ssB += dB * dB;
            }
        ssA += __shfl_xor(ssA, 16); ssA += __shfl_xor(ssA, 32);
        ssB += __shfl_xor(ssB, 16); ssB += __shfl_xor(ssB, 32);
        rsA = rsqrtf(ssA * (1.f / 128.f) + EPS_);
        rsB = rsqrtf(ssB * (1.f / 128.f) + EPS_);
    }

    // ---- xn -> LDS [token][feat] (b64 writes, wave-local rows), then fold
    //      b2 into yacc so it becomes the FFN2 accumulator/final value ----
    #pragma unroll
    for (int nt = 0; nt < 8; ++nt) {
        f32x4 g  = *(const f32x4*)(lng + nt * 16 + quad * 4);
        f32x4 bb = *(const f32x4*)(lnb + nt * 16 + quad * 4);
        f32x4 b2v = *(const f32x4*)(bv2 + nt * 16 + quad * 4);
        half4 ha, hb;
        #pragma unroll
        for (int r = 0; r < 4; ++r) {
            ha[r] = (_Float16)((yaccA[nt][r] - muA) * rsA * g[r] + bb[r]);
            hb[r] = (_Float16)((yaccB[nt][r] - muB) * rsB * g[r] + bb[r]);
        }
        *(half4*)(s_x + trA * 136 + nt * 16 + quad * 4) = ha;
        *(half4*)(s_x + trB * 136 + nt * 16 + quad * 4) = hb;
        yaccA[nt] += b2v;
        yaccB[nt] += b2v;
    }
    // same-wave DS ordering: rows trA/trB are wave-local.
    half8 xfragA[4], xfragB[4];
    #pragma unroll
    for (int kt = 0; kt < 4; ++kt) {
        xfragA[kt] = *(const half8*)(s_x + trA * 136 + kt * 32 + quad * 8);
        xfragB[kt] = *(const half8*)(s_x + trB * 136 + kt * 32 + quad * 8);
    }

    // ---- FFN: 4 chunks of 128 hidden; weight frags shared by both tiles ----
    for (int ch = 0; ch < 4; ++ch) {
        #pragma unroll
        for (int tl = 0; tl < 8; ++tl) {
            f32x4 bv = *(const f32x4*)(bv1 + ch * 128 + tl * 16 + quad * 4);
            f32x4 c1A = bv, c1B = bv;          // bias-seeded accumulators
            #pragma unroll
            for (int kt = 0; kt < 4; ++kt) {
                half8 wf = *(const half8*)(W1p + (((ch * 8 + tl) * 4 + kt) * 64 + lane) * 8);
                c1A = __builtin_amdgcn_mfma_f32_16x16x32_f16(wf, xfragA[kt], c1A, 0, 0, 0);
                c1B = __builtin_amdgcn_mfma_f32_16x16x32_f16(wf, xfragB[kt], c1B, 0, 0, 0);
            }
            half4 ha, hb;
            #pragma unroll
            for (int r = 0; r < 4; ++r) {
                float hxA = c1A[r];
                float eA = __expf(fminf(hxA, 30.f));
                float tA = 1.f + eA, t2A = tA * tA;
                ha[r] = (_Float16)(hxA * (t2A - 1.f) * __builtin_amdgcn_rcpf(t2A + 1.f));
                float hxB = c1B[r];
                float eB = __expf(fminf(hxB, 30.f));
                float tB = 1.f + eB, t2B = tB * tB;
                hb[r] = (_Float16)(hxB * (t2B - 1.f) * __builtin_amdgcn_rcpf(t2B + 1.f));
            }
            *(half4*)(s_x + trA * 136 + tl * 16 + quad * 4) = ha;
            *(half4*)(s_x + trB * 136 + tl * 16 + quad * 4) = hb;
        }
        half8 hfragA[4], hfragB[4];
        #pragma unroll
        for (int ks = 0; ks < 4; ++ks) {
            hfragA[ks] = *(const half8*)(s_x + trA * 136 + ks * 32 + quad * 8);
            hfragB[ks] = *(const half8*)(s_x + trB * 136 + ks * 32 + quad * 8);
        }
        #pragma unroll
        for (int nt = 0; nt < 8; ++nt) {
            #pragma unroll
            for (int ks = 0; ks < 4; ++ks) {
                half8 wf = *(const half8*)(W2p + ((nt * 16 + ch * 4 + ks) * 64 + lane) * 8);
                yaccA[nt] = __builtin_amdgcn_mfma_f32_16x16x32_f16(wf, hfragA[ks], yaccA[nt], 0, 0, 0);
                yaccB[nt] = __builtin_amdgcn_mfma_f32_16x16x32_f16(wf, hfragB[ks], yaccB[nt], 0, 0, 0);
            }
        }
    }

    // ---- out = yacc (already z + b2 + y)  (float4 stores) ----
    {
        float* orowA = ob + (tok0 + trA) * (long)ldo;
        float* orowB = ob + (tok0 + trB) * (long)ldo;
        #pragma unroll
        for (int nt = 0; nt < 8; ++nt) {
            *(f32x4*)(orowA + nt * 16 + quad * 4) = yaccA[nt];
            *(f32x4*)(orowB + nt * 16 + quad * 4) = yaccB[nt];
        }
    }
}

// ---------------------------------------------------------------------------
// enc0 = concat(e1, e2) @ WL2 + bL2
// ---------------------------------------------------------------------------
__global__ __launch_bounds__(256) void enc_combine(
    const float* __restrict__ e1, const float* __restrict__ e2,
    float* __restrict__ outp,
    const float* __restrict__ W, const float* __restrict__ bias)
{
    __shared__ float sc[32 * 256];
    const int tid = threadIdx.x;
    const long tok0 = (long)blockIdx.x * 32;
    #pragma unroll
    for (int r = 0; r < 4; ++r) {
        int u = tid + r * 256;
        int tok = u >> 5, c4 = u & 31;
        *(float4*)(sc + tok * 256 + c4 * 4)       = *(const float4*)(e1 + (tok0 + tok) * 128 + c4 * 4);
        *(float4*)(sc + tok * 256 + 128 + c4 * 4) = *(const float4*)(e2 + (tok0 + tok) * 128 + c4 * 4);
    }
    __syncthreads();
    const int j = tid & 63, tg = tid >> 6;
    float a0[8], a1[8];
    #pragma unroll
    for (int t = 0; t < 8; ++t) { a0[t] = 0.f; a1[t] = 0.f; }
    for (int i = 0; i < 256; i += 4) {
        float w0[4], w1[4];
        #pragma unroll
        for (int u = 0; u < 4; ++u) {
            w0[u] = W[(long)(i + u) * 128 + j];
            w1[u] = W[(long)(i + u) * 128 + j + 64];
        }
        #pragma unroll
        for (int t = 0; t < 8; ++t) {
            float4 xv = *(const float4*)(sc + (tg * 8 + t) * 256 + i);
            a0[t] += xv.x * w0[0] + xv.y * w0[1] + xv.z * w0[2] + xv.w * w0[3];
            a1[t] += xv.x * w1[0] + xv.y * w1[1] + xv.z * w1[2] + xv.w * w1[3];
        }
    }
    float b0 = bias[j], b1 = bias[j + 64];
    #pragma unroll
    for (int t = 0; t < 8; ++t) {
        int tok = tg * 8 + t;
        outp[(tok0 + tok) * 128 + j]      = a0[t] + b0;
        outp[(tok0 + tok) * 128 + j + 64] = a1[t] + b1;
    }
}

// ---------------------------------------------------------------------------
extern "C" void kernel_launch(void* const* d_in, const int* in_sizes, int n_in,
                              void* d_out, int out_size, void* d_ws, size_t ws_size,
                              hipStream_t stream)
{
    const float* src  = (const float*)d_in[0];
    const float* ln1g = (const float*)d_in[2];
    const float* ln1b = (const float*)d_in[3];
    const float* Wq   = (const float*)d_in[4];
    const float* Wk   = (const float*)d_in[5];
    const float* Wv   = (const float*)d_in[6];
    const float* Wfc  = (const float*)d_in[7];
    const float* ln2g = (const float*)d_in[8];
    const float* ln2b = (const float*)d_in[9];
    const float* W1   = (const float*)d_in[10];
    const float* b1   = (const float*)d_in[11];
    const float* W2   = (const float*)d_in[12];
    const float* b2   = (const float*)d_in[13];
    const float* WL2  = (const float*)d_in[14];
    const float* bL2  = (const float*)d_in[15];
    float* out = (float*)d_out;

    const long TOKS = (long)NTOK * 128;
    float* ws  = (float*)d_ws;
    float* XE1 = ws;
    float* XE2 = ws + TOKS;
    _Float16* V8 = (_Float16*)(ws + 2 * TOKS);          // 4*NTOK*64 fp16
    float* ATT = (float*)(V8 + 4L * NTOK * 64);         // 4*B*1024 f32
    _Float16* WPfc = (_Float16*)(ATT + 4 * B_ * 1024);  // 4*16384
    _Float16* WP1  = WPfc + 4L * 16384;                 // 4*65536
    _Float16* WP2  = WP1 + 4L * 65536;                  // 4*65536
    _Float16* WPq  = WP2 + 4L * 65536;                  // 4*16384
    _Float16* WPk  = WPq + 4L * 16384;                  // 4*8192
    _Float16* WPv  = WPk + 4L * 8192;                   // 4*8192
    if (ws_size < 205000000ULL) return;

    float* m1b  = out + TOKS;
    float* m2b  = out + 2 * TOKS;
    float* encb = out;
    const float* bufs[4] = { m1b, m2b, XE1, XE2 };

    // ---- pack weights to fp16 fragment order (d_ws re-poisoned per call) ----
    pack_b<<<dim3(64, 4),  dim3(256), 0, stream>>>(Wfc, WPfc, 128, 128);
    pack_b<<<dim3(256, 4), dim3(256), 0, stream>>>(W1,  WP1,  128, 512);
    pack_b<<<dim3(256, 4), dim3(256), 0, stream>>>(W2,  WP2,  512, 128);
    pack_b<<<dim3(64, 4),  dim3(256), 0, stream>>>(Wq,  WPq,  128, 128);
    pack_fold<<<dim3(32, 4), dim3(256), 0, stream>>>(Wk, WPk);
    pack_fold<<<dim3(32, 4), dim3(256), 0, stream>>>(Wv, WPv);

    // ---- stacked phase: streams {m1, m2, e1, e2} ----
    for (int l = 0; l < 4; ++l) {
        hipMemsetAsync(ATT, 0, 4 * B_ * 1024 * sizeof(float), stream);
        P4 qp, kp, op;
        int ldq, ldk;
        if (l == 0) {
            qp = P4{{ src, src + 128, src + 128, src }};  ldq = 256;
            kp = P4{{ src, src + 128, src, src + 128 }};  ldk = 256;
        } else {
            qp = P4{{ bufs[0], bufs[1], bufs[2], bufs[3] }}; ldq = 128;
            kp = qp; ldk = 128;
        }
        op = P4{{ bufs[0], bufs[1], bufs[2], bufs[3] }};
        enc_qkv_attn<<<dim3(4 * 2048), dim3(256), 0, stream>>>(
            qp, ldq, kp, ldk, V8, ATT,
            WPq + (long)l * 16384, WPk + (long)l * 8192, WPv + (long)l * 8192,
            ln1g + l * 128, ln1b + l * 128);
        enc_post_mfma<<<dim3(4 * 1024), dim3(256), 0, stream>>>(
            qp, ldq, op, 128, V8, ATT,
            WPfc + (long)l * 16384, ln2g + l * 128, ln2b + l * 128,
            WP1 + (long)l * 65536, b1 + l * 512,
            WP2 + (long)l * 65536, b2 + l * 128);
    }

    // ---- enc = concat(e1,e2) @ WL2 + bL2 ----
    enc_combine<<<dim3(4096), dim3(256), 0, stream>>>(XE1, XE2, encb, WL2, bL2);

    // ---- enc phase ----
    for (int l = 0; l < 4; ++l) {
        hipMemsetAsync(ATT, 0, B_ * 1024 * sizeof(float), stream);
        P4 p = P4{{ encb, encb, encb, encb }};
        enc_qkv_attn<<<dim3(2048), dim3(256), 0, stream>>>(
            p, 128, p, 128, V8, ATT,
            WPq + (long)l * 16384, WPk + (long)l * 8192, WPv + (long)l * 8192,
            ln1g + l * 128, ln1b + l * 128);
        enc_post_mfma<<<dim3(1024), dim3(256), 0, stream>>>(
            p, 128, p, 128, V8, ATT,
            WPfc + (long)l * 16384, ln2g + l * 128, ln2b + l * 128,
            WP1 + (long)l * 65536, b1 + l * 512,
            WP2 + (long)l * 65536, b2 + l * 128);
    }
}

// Round 8
// 5716.324 us; speedup vs baseline: 1.7900x; 1.0309x over previous
//
#include <hip/hip_runtime.h>
#include <math.h>

// Problem constants (from reference)
#define H_    8
#define DK_   16
#define DM_   128
#define DI_   512
#define B_    64
#define S_    2048
#define NTOK  131072          // B_*S_
#define EPS_  1e-6f
#define INV_TEMP 0.5f         // TEMP = 0.5*sqrt(16) = 2.0

typedef __attribute__((ext_vector_type(8))) _Float16 half8;
typedef __attribute__((ext_vector_type(4))) _Float16 half4;
typedef __attribute__((ext_vector_type(4))) float f32x4;

struct P4 { const float* p[4]; };

// Swizzled LDS byte offset for [row][128 halves] (256B rows):
// XOR of row&7 into bits 4-6 spreads 16-row column reads across all banks.
#define SWZ(row, bytecol) (((row) << 8) + ((bytecol) ^ (((row) & 7) << 4)))

// ---------------------------------------------------------------------------
// Pack a K x N f32 weight (row-major) into fp16 fragment order for
// mfma_f32_16x16x32_f16: flat[((nt*(K/32)+kt)*64 + lane)*8 + j] =
//   W[kt*32 + (lane>>4)*8 + j][nt*16 + (lane&15)].  blockIdx.y = layer.
// This layout is BOTH the B-frag of W and the A-frag of W^T (identical lane
// mapping), so swapped-operand MFMA (transposed output) needs no new pack.
// ---------------------------------------------------------------------------
__global__ __launch_bounds__(256) void pack_b(
    const float* __restrict__ W, _Float16* __restrict__ out, int K, int N)
{
    long base = (long)blockIdx.y * K * N;
    int idx = blockIdx.x * 256 + threadIdx.x;
    if (idx >= K * N) return;
    int j = idx & 7;
    int lane = (idx >> 3) & 63;
    int t = idx >> 9;                 // tile = nt*(K/32)+kt
    int KT = K >> 5;
    int nt = t / KT, kt = t - nt * KT;
    int k = kt * 32 + (lane >> 4) * 8 + j;
    int n = nt * 16 + (lane & 15);
    out[base + idx] = (_Float16)W[base + (long)k * N + n];
}

// ---------------------------------------------------------------------------
// Fold pair-mean (adjacent output columns) of a 128x128 weight into a 128x64
// fp16 fragment-packed weight.  folded[k][n] = 0.5*(W[k][2n] + W[k][2n+1]).
// ---------------------------------------------------------------------------
__global__ __launch_bounds__(256) void pack_fold(
    const float* __restrict__ W, _Float16* __restrict__ out)
{
    long wbase = (long)blockIdx.y * 128 * 128;
    long obase = (long)blockIdx.y * 128 * 64;
    int idx = blockIdx.x * 256 + threadIdx.x;   // 32 blocks * 256 = 8192
    int j = idx & 7;
    int lane = (idx >> 3) & 63;
    int t = idx >> 9;                 // tile = nt*4 + kt
    int nt = t >> 2, kt = t & 3;
    int k = kt * 32 + (lane >> 4) * 8 + j;
    int n = nt * 16 + (lane & 15);
    float v = 0.5f * (W[wbase + (long)k * 128 + 2 * n]
                    + W[wbase + (long)k * 128 + 2 * n + 1]);
    out[obase + idx] = (_Float16)v;
}

// ---------------------------------------------------------------------------
// Kernel A (MFMA, unchanged from round 7 — verified 5893 total).
// ---------------------------------------------------------------------------
__global__ __launch_bounds__(256) void enc_qkv_attn(
    P4 qp, int ldq, P4 kp, int ldk,
    _Float16* __restrict__ v8, float* __restrict__ att,
    const _Float16* __restrict__ Wqp, const _Float16* __restrict__ Wkp,
    const _Float16* __restrict__ Wvp,
    const float* __restrict__ lng, const float* __restrict__ lnb)
{
    __shared__ _Float16 s_xn[64 * 136];   // XN fp16, then q fp16 (17.4KB)
    __shared__ _Float16 s_k[64 * 72];     // k8 fp16 [tok][64+8 pad] (9.2KB)
    __shared__ float s_p[1024];           // score accumulator (4KB)

    const int tid  = threadIdx.x;
    const int w    = tid >> 6;            // wave 0..3
    const int lane = tid & 63;
    const int quad = lane >> 4, l16 = lane & 15;
    const int bx   = blockIdx.x;
    const int s    = bx >> 11;
    const int blk  = bx & 2047;
    const long tok0 = (long)blk * 64;
    const int b = blk >> 5;
    const int trow = w * 16 + l16;        // this lane's token row (0..63)
    const long gtok = tok0 + trow;

    const float* qb = qp.p[s];
    const float* kb = kp.p[s];
    _Float16* v8s = v8 + (long)s * ((long)NTOK * 64) + tok0 * 64;
    float* atts = att + (long)s * (B_ * 1024) + (long)b * 1024;

    for (int i = tid; i < 1024; i += 256) s_p[i] = 0.f;

    // ---- K/V input fragments straight from global (raw k-input) ----
    half8 xk[4];
    #pragma unroll
    for (int kt = 0; kt < 4; ++kt) {
        f32x4 a = *(const f32x4*)(kb + gtok * (long)ldk + kt * 32 + quad * 8);
        f32x4 c = *(const f32x4*)(kb + gtok * (long)ldk + kt * 32 + quad * 8 + 4);
        #pragma unroll
        for (int r = 0; r < 4; ++r) {
            xk[kt][r]     = (_Float16)a[r];
            xk[kt][r + 4] = (_Float16)c[r];
        }
    }

    // ---- K proj (folded) MFMA -> k8^T -> s_k fp16 [tok][feat] ----
    #pragma unroll
    for (int nt = 0; nt < 4; ++nt) {
        f32x4 c = {0.f, 0.f, 0.f, 0.f};
        #pragma unroll
        for (int kt = 0; kt < 4; ++kt) {
            half8 wf = *(const half8*)(Wkp + ((nt * 4 + kt) * 64 + lane) * 8);
            c = __builtin_amdgcn_mfma_f32_16x16x32_f16(wf, xk[kt], c, 0, 0, 0);
        }
        half4 hv;
        #pragma unroll
        for (int r = 0; r < 4; ++r) hv[r] = (_Float16)c[r];
        *(half4*)(s_k + trow * 72 + nt * 16 + quad * 4) = hv;
    }

    // ---- V proj (folded) MFMA -> global v8 fp16 [tok][feat] ----
    #pragma unroll
    for (int nt = 0; nt < 4; ++nt) {
        f32x4 c = {0.f, 0.f, 0.f, 0.f};
        #pragma unroll
        for (int kt = 0; kt < 4; ++kt) {
            half8 wf = *(const half8*)(Wvp + ((nt * 4 + kt) * 64 + lane) * 8);
            c = __builtin_amdgcn_mfma_f32_16x16x32_f16(wf, xk[kt], c, 0, 0, 0);
        }
        half4 hv;
        #pragma unroll
        for (int r = 0; r < 4; ++r) hv[r] = (_Float16)c[r];
        *(half4*)(v8s + (long)trow * 64 + nt * 16 + quad * 4) = hv;
    }

    // ---- LN1 from global q-input; stats via in-register + quad butterfly ----
    f32x4 xq[8];       // token trow, feats quad*32 .. quad*32+31
    #pragma unroll
    for (int k = 0; k < 8; ++k)
        xq[k] = *(const f32x4*)(qb + gtok * (long)ldq + quad * 32 + k * 4);
    float mu, rs;
    {
        float sm = 0.f;
        #pragma unroll
        for (int k = 0; k < 8; ++k)
            #pragma unroll
            for (int r = 0; r < 4; ++r) sm += xq[k][r];
        sm += __shfl_xor(sm, 16); sm += __shfl_xor(sm, 32);
        mu = sm * (1.f / 128.f);
        float ss = 0.f;
        #pragma unroll
        for (int k = 0; k < 8; ++k)
            #pragma unroll
            for (int r = 0; r < 4; ++r) { float d = xq[k][r] - mu; ss += d * d; }
        ss += __shfl_xor(ss, 16); ss += __shfl_xor(ss, 32);
        rs = rsqrtf(ss * (1.f / 128.f) + EPS_);
    }
    // normalized XN -> s_xn fp16 [tok][feat]
    #pragma unroll
    for (int k = 0; k < 8; ++k) {
        f32x4 g  = *(const f32x4*)(lng + quad * 32 + k * 4);
        f32x4 bb = *(const f32x4*)(lnb + quad * 32 + k * 4);
        half4 hv;
        #pragma unroll
        for (int r = 0; r < 4; ++r)
            hv[r] = (_Float16)((xq[k][r] - mu) * rs * g[r] + bb[r]);
        *(half4*)(s_xn + trow * 136 + quad * 32 + k * 4) = hv;
    }

    // ---- Q fragments (wave-local rows; same-wave DS ordering) + MFMA ----
    half8 xn[4];
    #pragma unroll
    for (int kt = 0; kt < 4; ++kt)
        xn[kt] = *(const half8*)(s_xn + trow * 136 + kt * 32 + quad * 8);
    f32x4 qa[8];
    #pragma unroll
    for (int nt = 0; nt < 8; ++nt) {
        f32x4 c = {0.f, 0.f, 0.f, 0.f};
        #pragma unroll
        for (int kt = 0; kt < 4; ++kt) {
            half8 wf = *(const half8*)(Wqp + ((nt * 4 + kt) * 64 + lane) * 8);
            c = __builtin_amdgcn_mfma_f32_16x16x32_f16(wf, xn[kt], c, 0, 0, 0);
        }
        qa[nt] = c;
    }
    // overwrite s_xn with q fp16 (reads above precede writes in program order)
    #pragma unroll
    for (int nt = 0; nt < 8; ++nt) {
        half4 hv;
        #pragma unroll
        for (int r = 0; r < 4; ++r) hv[r] = (_Float16)qa[nt][r];
        *(half4*)(s_xn + trow * 136 + nt * 16 + quad * 4) = hv;
    }

    __syncthreads();   // barrier 1: q, k8, s_p-zero visible block-wide

    // ---- score partials over this wave's 16 tokens (lane j: feats j, j+64) ----
    {
        const int j = lane;
        const int h0 = j >> 4, h1 = (j + 64) >> 4;
        float p0[8], p1[8];
        #pragma unroll
        for (int e = 0; e < 8; ++e) { p0[e] = 0.f; p1[e] = 0.f; }
        #pragma unroll
        for (int t = 0; t < 16; ++t) {
            int tok = w * 16 + t;
            float q0 = (float)s_xn[tok * 136 + j];
            float q1 = (float)s_xn[tok * 136 + j + 64];
            half8 k0 = *(const half8*)(s_k + tok * 72 + h0 * 8);
            half8 k1 = *(const half8*)(s_k + tok * 72 + h1 * 8);
            #pragma unroll
            for (int e = 0; e < 8; ++e) {
                p0[e] += q0 * (float)k0[e];
                p1[e] += q1 * (float)k1[e];
            }
        }
        // bank-staggered LDS atomics (e-order rotated by j>>2 -> 2-way max)
        #pragma unroll
        for (int ee = 0; ee < 8; ++ee) {
            int e = (ee + (j >> 2)) & 7;
            atomicAdd(&s_p[j * 8 + e], p0[e]);
            atomicAdd(&s_p[(j + 64) * 8 + e], p1[e]);
        }
    }
    __syncthreads();   // barrier 2: all partials in s_p
    for (int i = tid; i < 1024; i += 256)
        atomicAdd(atts + i, s_p[i]);
}

// ---------------------------------------------------------------------------
// Kernel C (MFMA, fp16, swapped operands, 8 waves / 256 tokens per block):
// wave w owns rows {w*16+l16, w*16+l16+128}; per-wave code = proven 2-tile
// structure.  8 waves share each weight-fragment L1 window -> L2 weight
// traffic ~halved.  s_att overlays the swizzled s_x buffer (64KB exactly);
// XOR swizzle (row&7)<<4 makes ds_read_b128 conflict-free.  y+b2 stored to
// global early (frees 64 VGPRs for load pipelining, launch_bounds 512,4);
// read back at the end and added to the FFN accumulator.
// ---------------------------------------------------------------------------
__global__ __launch_bounds__(512, 4) void enc_post_mfma(
    P4 xp, int ldx, P4 op, int ldo,
    const _Float16* __restrict__ v8, const float* __restrict__ att,
    const _Float16* __restrict__ Wfcp,
    const float* __restrict__ lng, const float* __restrict__ lnb,
    const _Float16* __restrict__ W1p, const float* __restrict__ bv1,
    const _Float16* __restrict__ W2p, const float* __restrict__ bv2)
{
    __shared__ __align__(16) unsigned char s_raw[65536];  // s_att (4KB) then s_x
    float* s_att = (float*)s_raw;
    char*  s8    = (char*)s_raw;       // swizzled [256 rows][256B] fp16

    const int tid  = threadIdx.x;
    const int w    = tid >> 6;          // wave 0..7
    const int lane = tid & 63;
    const int quad = lane >> 4, l16 = lane & 15;
    const int bx   = blockIdx.x;
    const int s    = bx >> 9;           // 512 blocks per stream
    const int blk  = bx & 511;
    const long tok0 = (long)blk * 256;
    const int b = blk >> 3;             // 8 blocks per sequence

    const float* xb = xp.p[s];
    float* ob = (float*)op.p[s];
    const _Float16* v8s = v8 + (long)s * ((long)NTOK * 64) + tok0 * 64;
    const float* atts = att + (long)s * (B_ * 1024) + (long)b * 1024;

    const int trA = w * 16 + l16;       // tile-A token row (0..127)
    const int trB = trA + 128;          // tile-B token row (128..255)

    if (tid < 128) {                    // softmax rows h*16+d
        float sc[8];
        #pragma unroll
        for (int e = 0; e < 8; ++e) sc[e] = atts[tid * 8 + e] * INV_TEMP;
        float m = sc[0];
        #pragma unroll
        for (int e = 1; e < 8; ++e) m = fmaxf(m, sc[e]);
        float sum = 0.f;
        #pragma unroll
        for (int e = 0; e < 8; ++e) { sc[e] = expf(sc[e] - m); sum += sc[e]; }
        float inv = 1.f / sum;
        #pragma unroll
        for (int e = 0; e < 8; ++e) s_att[tid * 8 + e] = sc[e] * inv;
    }
    __syncthreads();                    // s_att ready

    // ---- v rows for both tiles ----
    half8 hvA[8], hvB[8];
    {
        const _Float16* vra = v8s + (long)trA * 64;
        const _Float16* vrb = v8s + (long)trB * 64;
        #pragma unroll
        for (int j = 0; j < 8; ++j) {
            hvA[j] = *(const half8*)(vra + j * 8);
            hvB[j] = *(const half8*)(vrb + j * 8);
        }
    }

    // ---- attn apply -> fragments for both tiles; s_att reads shared ----
    half8 afragA[4], afragB[4];
    {
        float aoA[4][8], aoB[4][8];
        #pragma unroll
        for (int j = 0; j < 8; ++j) {
            #pragma unroll
            for (int kt = 0; kt < 4; ++kt) {
                const float* ar = s_att + (j * 16 + kt * 4 + quad) * 8;
                float4 a0 = *(const float4*)ar;
                float4 a1 = *(const float4*)(ar + 4);
                float vA = (float)hvA[j][0] * a0.x + (float)hvA[j][1] * a0.y
                         + (float)hvA[j][2] * a0.z + (float)hvA[j][3] * a0.w
                         + (float)hvA[j][4] * a1.x + (float)hvA[j][5] * a1.y
                         + (float)hvA[j][6] * a1.z + (float)hvA[j][7] * a1.w;
                float vB = (float)hvB[j][0] * a0.x + (float)hvB[j][1] * a0.y
                         + (float)hvB[j][2] * a0.z + (float)hvB[j][3] * a0.w
                         + (float)hvB[j][4] * a1.x + (float)hvB[j][5] * a1.y
                         + (float)hvB[j][6] * a1.z + (float)hvB[j][7] * a1.w;
                aoA[kt][j] = vA;
                aoB[kt][j] = vB;
            }
        }
        #pragma unroll
        for (int kt = 0; kt < 4; ++kt)
            #pragma unroll
            for (int j = 0; j < 8; ++j) {
                afragA[kt][j] = (_Float16)aoA[kt][j];
                afragB[kt][j] = (_Float16)aoB[kt][j];
            }
    }

    // ---- Wfc swapped, residual-seeded: yacc = x + attn_out @ Wfc ----
    f32x4 yaccA[8], yaccB[8];
    {
        const float* xrowA = xb + (tok0 + trA) * (long)ldx;
        const float* xrowB = xb + (tok0 + trB) * (long)ldx;
        #pragma unroll
        for (int nt = 0; nt < 8; ++nt) {
            yaccA[nt] = *(const f32x4*)(xrowA + nt * 16 + quad * 4);
            yaccB[nt] = *(const f32x4*)(xrowB + nt * 16 + quad * 4);
        }
    }
    #pragma unroll
    for (int nt = 0; nt < 8; ++nt) {
        #pragma unroll
        for (int kt = 0; kt < 4; ++kt) {
            half8 wf = *(const half8*)(Wfcp + ((nt * 4 + kt) * 64 + lane) * 8);
            yaccA[nt] = __builtin_amdgcn_mfma_f32_16x16x32_f16(wf, afragA[kt], yaccA[nt], 0, 0, 0);
            yaccB[nt] = __builtin_amdgcn_mfma_f32_16x16x32_f16(wf, afragB[kt], yaccB[nt], 0, 0, 0);
        }
    }

    // ---- LN2 per tile: in-lane 32-sum + quad butterfly (xor 16, 32) ----
    float muA, rsA, muB, rsB;
    {
        float smA = 0.f, smB = 0.f;
        #pragma unroll
        for (int nt = 0; nt < 8; ++nt)
            #pragma unroll
            for (int r = 0; r < 4; ++r) { smA += yaccA[nt][r]; smB += yaccB[nt][r]; }
        smA += __shfl_xor(smA, 16); smA += __shfl_xor(smA, 32);
        smB += __shfl_xor(smB, 16); smB += __shfl_xor(smB, 32);
        muA = smA * (1.f / 128.f); muB = smB * (1.f / 128.f);
        float ssA = 0.f, ssB = 0.f;
        #pragma unroll
        for (int nt = 0; nt < 8; ++nt)
            #pragma unroll
            for (int r = 0; r < 4; ++r) {
                float dA = yaccA[nt][r] - muA; ssA += dA * dA;
                float dB = yaccB[nt][r] - muB; ssB += dB * dB;
            }
        ssA += __shfl_xor(ssA, 16); ssA += __shfl_xor(ssA, 32);
        ssB += __shfl_xor(ssB, 16); ssB += __shfl_xor(ssB, 32);
        rsA = rsqrtf(ssA * (1.f / 128.f) + EPS_);
        rsB = rsqrtf(ssB * (1.f / 128.f) + EPS_);
    }

    __syncthreads();   // WAR: all waves done reading s_att before s_x overlay

    // ---- xn -> swizzled LDS; y+b2 -> global (frees yacc regs) ----
    {
        float* orowA = ob + (tok0 + trA) * (long)ldo;
        float* orowB = ob + (tok0 + trB) * (long)ldo;
        #pragma unroll
        for (int nt = 0; nt < 8; ++nt) {
            f32x4 g  = *(const f32x4*)(lng + nt * 16 + quad * 4);
            f32x4 bb = *(const f32x4*)(lnb + nt * 16 + quad * 4);
            f32x4 b2v = *(const f32x4*)(bv2 + nt * 16 + quad * 4);
            half4 ha, hb;
            #pragma unroll
            for (int r = 0; r < 4; ++r) {
                ha[r] = (_Float16)((yaccA[nt][r] - muA) * rsA * g[r] + bb[r]);
                hb[r] = (_Float16)((yaccB[nt][r] - muB) * rsB * g[r] + bb[r]);
            }
            *(half4*)(s8 + SWZ(trA, nt * 32 + quad * 8)) = ha;
            *(half4*)(s8 + SWZ(trB, nt * 32 + quad * 8)) = hb;
            *(f32x4*)(orowA + nt * 16 + quad * 4) = yaccA[nt] + b2v;
            *(f32x4*)(orowB + nt * 16 + quad * 4) = yaccB[nt] + b2v;
        }
    }
    // same-wave DS ordering: rows trA/trB are wave-local.
    half8 xfragA[4], xfragB[4];
    #pragma unroll
    for (int kt = 0; kt < 4; ++kt) {
        xfragA[kt] = *(const half8*)(s8 + SWZ(trA, kt * 64 + quad * 16));
        xfragB[kt] = *(const half8*)(s8 + SWZ(trB, kt * 64 + quad * 16));
    }

    // ---- FFN: 4 chunks of 128 hidden; weight frags shared by both tiles ----
    f32x4 zaccA[8], zaccB[8];
    #pragma unroll
    for (int nt = 0; nt < 8; ++nt) {
        zaccA[nt] = f32x4{0.f, 0.f, 0.f, 0.f};
        zaccB[nt] = f32x4{0.f, 0.f, 0.f, 0.f};
    }
    for (int ch = 0; ch < 4; ++ch) {
        #pragma unroll
        for (int tl = 0; tl < 8; ++tl) {
            f32x4 bv = *(const f32x4*)(bv1 + ch * 128 + tl * 16 + quad * 4);
            f32x4 c1A = bv, c1B = bv;          // bias-seeded accumulators
            #pragma unroll
            for (int kt = 0; kt < 4; ++kt) {
                half8 wf = *(const half8*)(W1p + (((ch * 8 + tl) * 4 + kt) * 64 + lane) * 8);
                c1A = __builtin_amdgcn_mfma_f32_16x16x32_f16(wf, xfragA[kt], c1A, 0, 0, 0);
                c1B = __builtin_amdgcn_mfma_f32_16x16x32_f16(wf, xfragB[kt], c1B, 0, 0, 0);
            }
            half4 ha, hb;
            #pragma unroll
            for (int r = 0; r < 4; ++r) {
                float hxA = c1A[r];
                float eA = __expf(fminf(hxA, 30.f));
                float tA = 1.f + eA, t2A = tA * tA;
                ha[r] = (_Float16)(hxA * (t2A - 1.f) * __builtin_amdgcn_rcpf(t2A + 1.f));
                float hxB = c1B[r];
                float eB = __expf(fminf(hxB, 30.f));
                float tB = 1.f + eB, t2B = tB * tB;
                hb[r] = (_Float16)(hxB * (t2B - 1.f) * __builtin_amdgcn_rcpf(t2B + 1.f));
            }
            *(half4*)(s8 + SWZ(trA, tl * 32 + quad * 8)) = ha;
            *(half4*)(s8 + SWZ(trB, tl * 32 + quad * 8)) = hb;
        }
        half8 hfragA[4], hfragB[4];
        #pragma unroll
        for (int ks = 0; ks < 4; ++ks) {
            hfragA[ks] = *(const half8*)(s8 + SWZ(trA, ks * 64 + quad * 16));
            hfragB[ks] = *(const half8*)(s8 + SWZ(trB, ks * 64 + quad * 16));
        }
        #pragma unroll
        for (int nt = 0; nt < 8; ++nt) {
            #pragma unroll
            for (int ks = 0; ks < 4; ++ks) {
                half8 wf = *(const half8*)(W2p + ((nt * 16 + ch * 4 + ks) * 64 + lane) * 8);
                zaccA[nt] = __builtin_amdgcn_mfma_f32_16x16x32_f16(wf, hfragA[ks], zaccA[nt], 0, 0, 0);
                zaccB[nt] = __builtin_amdgcn_mfma_f32_16x16x32_f16(wf, hfragB[ks], zaccB[nt], 0, 0, 0);
            }
        }
    }

    // ---- out = (y + b2, read back) + z  (float4 RMW, same-lane addresses) ----
    {
        float* orowA = ob + (tok0 + trA) * (long)ldo;
        float* orowB = ob + (tok0 + trB) * (long)ldo;
        #pragma unroll
        for (int nt = 0; nt < 8; ++nt) {
            f32x4 ybA = *(const f32x4*)(orowA + nt * 16 + quad * 4);
            f32x4 ybB = *(const f32x4*)(orowB + nt * 16 + quad * 4);
            *(f32x4*)(orowA + nt * 16 + quad * 4) = ybA + zaccA[nt];
            *(f32x4*)(orowB + nt * 16 + quad * 4) = ybB + zaccB[nt];
        }
    }
}

// ---------------------------------------------------------------------------
// enc0 = concat(e1, e2) @ WL2 + bL2
// ---------------------------------------------------------------------------
__global__ __launch_bounds__(256) void enc_combine(
    const float* __restrict__ e1, const float* __restrict__ e2,
    float* __restrict__ outp,
    const float* __restrict__ W, const float* __restrict__ bias)
{
    __shared__ float sc[32 * 256];
    const int tid = threadIdx.x;
    const long tok0 = (long)blockIdx.x * 32;
    #pragma unroll
    for (int r = 0; r < 4; ++r) {
        int u = tid + r * 256;
        int tok = u >> 5, c4 = u & 31;
        *(float4*)(sc + tok * 256 + c4 * 4)       = *(const float4*)(e1 + (tok0 + tok) * 128 + c4 * 4);
        *(float4*)(sc + tok * 256 + 128 + c4 * 4) = *(const float4*)(e2 + (tok0 + tok) * 128 + c4 * 4);
    }
    __syncthreads();
    const int j = tid & 63, tg = tid >> 6;
    float a0[8], a1[8];
    #pragma unroll
    for (int t = 0; t < 8; ++t) { a0[t] = 0.f; a1[t] = 0.f; }
    for (int i = 0; i < 256; i += 4) {
        float w0[4], w1[4];
        #pragma unroll
        for (int u = 0; u < 4; ++u) {
            w0[u] = W[(long)(i + u) * 128 + j];
            w1[u] = W[(long)(i + u) * 128 + j + 64];
        }
        #pragma unroll
        for (int t = 0; t < 8; ++t) {
            float4 xv = *(const float4*)(sc + (tg * 8 + t) * 256 + i);
            a0[t] += xv.x * w0[0] + xv.y * w0[1] + xv.z * w0[2] + xv.w * w0[3];
            a1[t] += xv.x * w1[0] + xv.y * w1[1] + xv.z * w1[2] + xv.w * w1[3];
        }
    }
    float b0 = bias[j], b1 = bias[j + 64];
    #pragma unroll
    for (int t = 0; t < 8; ++t) {
        int tok = tg * 8 + t;
        outp[(tok0 + tok) * 128 + j]      = a0[t] + b0;
        outp[(tok0 + tok) * 128 + j + 64] = a1[t] + b1;
    }
}

// ---------------------------------------------------------------------------
extern "C" void kernel_launch(void* const* d_in, const int* in_sizes, int n_in,
                              void* d_out, int out_size, void* d_ws, size_t ws_size,
                              hipStream_t stream)
{
    const float* src  = (const float*)d_in[0];
    const float* ln1g = (const float*)d_in[2];
    const float* ln1b = (const float*)d_in[3];
    const float* Wq   = (const float*)d_in[4];
    const float* Wk   = (const float*)d_in[5];
    const float* Wv   = (const float*)d_in[6];
    const float* Wfc  = (const float*)d_in[7];
    const float* ln2g = (const float*)d_in[8];
    const float* ln2b = (const float*)d_in[9];
    const float* W1   = (const float*)d_in[10];
    const float* b1   = (const float*)d_in[11];
    const float* W2   = (const float*)d_in[12];
    const float* b2   = (const float*)d_in[13];
    const float* WL2  = (const float*)d_in[14];
    const float* bL2  = (const float*)d_in[15];
    float* out = (float*)d_out;

    const long TOKS = (long)NTOK * 128;
    float* ws  = (float*)d_ws;
    float* XE1 = ws;
    float* XE2 = ws + TOKS;
    _Float16* V8 = (_Float16*)(ws + 2 * TOKS);          // 4*NTOK*64 fp16
    float* ATT = (float*)(V8 + 4L * NTOK * 64);         // 4*B*1024 f32
    _Float16* WPfc = (_Float16*)(ATT + 4 * B_ * 1024);  // 4*16384
    _Float16* WP1  = WPfc + 4L * 16384;                 // 4*65536
    _Float16* WP2  = WP1 + 4L * 65536;                  // 4*65536
    _Float16* WPq  = WP2 + 4L * 65536;                  // 4*16384
    _Float16* WPk  = WPq + 4L * 16384;                  // 4*8192
    _Float16* WPv  = WPk + 4L * 8192;                   // 4*8192
    if (ws_size < 205000000ULL) return;

    float* m1b  = out + TOKS;
    float* m2b  = out + 2 * TOKS;
    float* encb = out;
    const float* bufs[4] = { m1b, m2b, XE1, XE2 };

    // ---- pack weights to fp16 fragment order (d_ws re-poisoned per call) ----
    pack_b<<<dim3(64, 4),  dim3(256), 0, stream>>>(Wfc, WPfc, 128, 128);
    pack_b<<<dim3(256, 4), dim3(256), 0, stream>>>(W1,  WP1,  128, 512);
    pack_b<<<dim3(256, 4), dim3(256), 0, stream>>>(W2,  WP2,  512, 128);
    pack_b<<<dim3(64, 4),  dim3(256), 0, stream>>>(Wq,  WPq,  128, 128);
    pack_fold<<<dim3(32, 4), dim3(256), 0, stream>>>(Wk, WPk);
    pack_fold<<<dim3(32, 4), dim3(256), 0, stream>>>(Wv, WPv);

    // ---- stacked phase: streams {m1, m2, e1, e2} ----
    for (int l = 0; l < 4; ++l) {
        hipMemsetAsync(ATT, 0, 4 * B_ * 1024 * sizeof(float), stream);
        P4 qp, kp, op;
        int ldq, ldk;
        if (l == 0) {
            qp = P4{{ src, src + 128, src + 128, src }};  ldq = 256;
            kp = P4{{ src, src + 128, src, src + 128 }};  ldk = 256;
        } else {
            qp = P4{{ bufs[0], bufs[1], bufs[2], bufs[3] }}; ldq = 128;
            kp = qp; ldk = 128;
        }
        op = P4{{ bufs[0], bufs[1], bufs[2], bufs[3] }};
        enc_qkv_attn<<<dim3(4 * 2048), dim3(256), 0, stream>>>(
            qp, ldq, kp, ldk, V8, ATT,
            WPq + (long)l * 16384, WPk + (long)l * 8192, WPv + (long)l * 8192,
            ln1g + l * 128, ln1b + l * 128);
        enc_post_mfma<<<dim3(4 * 512), dim3(512), 0, stream>>>(
            qp, ldq, op, 128, V8, ATT,
            WPfc + (long)l * 16384, ln2g + l * 128, ln2b + l * 128,
            WP1 + (long)l * 65536, b1 + l * 512,
            WP2 + (long)l * 65536, b2 + l * 128);
    }

    // ---- enc = concat(e1,e2) @ WL2 + bL2 ----
    enc_combine<<<dim3(4096), dim3(256), 0, stream>>>(XE1, XE2, encb, WL2, bL2);

    // ---- enc phase ----
    for (int l = 0; l < 4; ++l) {
        hipMemsetAsync(ATT, 0, B_ * 1024 * sizeof(float), stream);
        P4 p = P4{{ encb, encb, encb, encb }};
        enc_qkv_attn<<<dim3(2048), dim3(256), 0, stream>>>(
            p, 128, p, 128, V8, ATT,
            WPq + (long)l * 16384, WPk + (long)l * 8192, WPv + (long)l * 8192,
            ln1g + l * 128, ln1b + l * 128);
        enc_post_mfma<<<dim3(512), dim3(512), 0, stream>>>(
            p, 128, p, 128, V8, ATT,
            WPfc + (long)l * 16384, ln2g + l * 128, ln2b + l * 128,
            WP1 + (long)l * 65536, b1 + l * 512,
            WP2 + (long)l * 65536, b2 + l * 128);
    }
}